// Round 3
// baseline (48525.601 us; speedup 1.0000x reference)
//
#include <hip/hip_runtime.h>

#define NB 256
#define NT 512

constexpr int BATCH = 1024;
constexpr int TSTEPS = 20;
constexpr int IND = 13;
constexpr int OD = 9;
constexpr int SU = 32;
constexpr int HID = 32;
constexpr int ITERS = 20;
constexpr float LR = 0.1f;
constexpr float AB1 = 0.9f;
constexpr float AB2 = 0.999f;
constexpr float AEPS = 1e-8f;

// bounded-spin cap: expected waits are ~µs; this is seconds. On trip, the
// block proceeds -> run terminates with wrong output instead of hanging.
constexpr unsigned SPIN_CAP = 1u << 27;

// workspace byte offsets
constexpr size_t OFF_TAGS  = 0;       // u32 [2][NB]   (zeroed by memset)
constexpr size_t OFF_TAGS2 = 2048;    // u32 [NB]      (zeroed by memset)
constexpr size_t OFF_ERRP  = 3072;    // f32 [NB]
constexpr size_t OFF_PART  = 4096;    // f32 [2][NB][SU]
constexpr size_t OFF_WIHT  = 69632;   // f32 [45][32]
constexpr size_t OFF_WHHT  = 75392;   // f32 [32][32]
constexpr size_t WS_NEEDED = OFF_WHHT + 32 * 32 * 4;  // 79488 B

__global__ void prep_kernel(const float* __restrict__ Wih,
                            const float* __restrict__ Whh,
                            char* __restrict__ ws) {
  float* WihT = reinterpret_cast<float*>(ws + OFF_WIHT);
  float* WhhT = reinterpret_cast<float*>(ws + OFF_WHHT);
  int tid = blockIdx.x * blockDim.x + threadIdx.x;
  int nt = gridDim.x * blockDim.x;
  for (int idx = tid; idx < 32 * 45; idx += nt) {
    int i = idx / 45, c = idx % 45;
    WihT[c * 32 + i] = Wih[idx];
  }
  for (int idx = tid; idx < 32 * 32; idx += nt) {
    int i = idx >> 5, j = idx & 31;
    WhhT[j * 32 + i] = Whh[idx];
  }
}

__global__ __launch_bounds__(NT) void emb_kernel(
    const float* __restrict__ X, const float* __restrict__ Y,
    const float* __restrict__ pW1, const float* __restrict__ pb1,
    const float* __restrict__ pW2, const float* __restrict__ pb2,
    const float* __restrict__ pW3, const float* __restrict__ pb3,
    const float* __restrict__ pW4, const float* __restrict__ pb4,
    const float* __restrict__ pWih, const float* __restrict__ pWhh,
    const float* __restrict__ pbih, const float* __restrict__ pbhh,
    const float* __restrict__ pWd, const float* __restrict__ pbd,
    char* __restrict__ ws, float* __restrict__ out) {
  const int tid = threadIdx.x;
  const int bid = blockIdx.x;
  const int row0 = bid * 4;

  unsigned* tags  = reinterpret_cast<unsigned*>(ws + OFF_TAGS);   // [2][NB]
  unsigned* tags2 = reinterpret_cast<unsigned*>(ws + OFF_TAGS2);  // [NB]
  float* errp = reinterpret_cast<float*>(ws + OFF_ERRP);          // [NB]
  float* part = reinterpret_cast<float*>(ws + OFF_PART);          // [2][NB][SU]
  const float* WihT = reinterpret_cast<const float*>(ws + OFF_WIHT);
  const float* WhhT = reinterpret_cast<const float*>(ws + OFF_WHHT);

  __shared__ alignas(16) float s[4][SU];
  __shared__ alignas(16) float mAd[4][SU];
  __shared__ alignas(16) float vAd[4][SU];
  __shared__ alignas(16) float hOld[4][HID];
  __shared__ alignas(16) float hNew[4][HID];
  __shared__ alignas(16) float h1[4][128];
  __shared__ alignas(16) float h2[4][256];
  __shared__ alignas(16) float h3[4][256];
  __shared__ alignas(16) float wv[4][SU];
  __shared__ alignas(16) float da[4][HID];
  __shared__ alignas(16) float dwb[4][SU];
  __shared__ alignas(16) float dsb[4][SU];
  __shared__ alignas(16) float tmp4[4][4][128];
  __shared__ float xs[4][IND];
  __shared__ float ysd[4][OD];
  __shared__ float dadec[4][OD];
  __shared__ float mu[SU];
  __shared__ float red[8][SU];

  // bounded spin until *tagp >= tgt (returns regardless after SPIN_CAP polls)
  auto spin_ge = [&](unsigned* tagp, unsigned tgt) {
    unsigned n = 0;
    while (__hip_atomic_load(tagp, __ATOMIC_RELAXED,
                             __HIP_MEMORY_SCOPE_AGENT) < tgt) {
      __builtin_amdgcn_s_sleep(1);
      if (++n >= SPIN_CAP) break;
    }
  };

  // ---- layer routines (all 512 threads enter each; internal barriers uniform)

  // L1 fwd: h1[r][j] = relu(b1[j] + sum_k s[r][k] W1[k*128+j]); 512 = 4r x 128j
  auto fwd_l1 = [&]() {
    int r = tid >> 7, j = tid & 127;
    const float* sr = &s[0][0] + r * SU;
    float a = pb1[j];
#pragma unroll
    for (int k = 0; k < SU; k += 4) {
      float4 h4 = *reinterpret_cast<const float4*>(sr + k);
      a += h4.x * pW1[(k    ) * 128 + j];
      a += h4.y * pW1[(k + 1) * 128 + j];
      a += h4.z * pW1[(k + 2) * 128 + j];
      a += h4.w * pW1[(k + 3) * 128 + j];
    }
    h1[r][j] = fmaxf(a, 0.f);
  };

  // wide fwd (OUT=256): 512 threads = 4r x 128 j-pairs, relu
  auto fwd_wide = [&](const float* __restrict__ W, const float* __restrict__ bias,
                      const float* hin, int K, float* hout) {
    int r = tid >> 7, j = (tid & 127) * 2;
    const float* hr = hin + r * K;
    float a0 = bias[j], a1 = bias[j + 1];
#pragma unroll 4
    for (int k = 0; k < K; k += 4) {
      float4 h4 = *reinterpret_cast<const float4*>(hr + k);
      float2 w0 = *reinterpret_cast<const float2*>(W + (k    ) * 256 + j);
      float2 w1 = *reinterpret_cast<const float2*>(W + (k + 1) * 256 + j);
      float2 w2 = *reinterpret_cast<const float2*>(W + (k + 2) * 256 + j);
      float2 w3 = *reinterpret_cast<const float2*>(W + (k + 3) * 256 + j);
      a0 += h4.x * w0.x + h4.y * w1.x + h4.z * w2.x + h4.w * w3.x;
      a1 += h4.x * w0.y + h4.y * w1.y + h4.z * w2.y + h4.w * w3.y;
    }
    hout[r * 256 + j]     = fmaxf(a0, 0.f);
    hout[r * 256 + j + 1] = fmaxf(a1, 0.f);
  };

  // L4 fwd: wv[r][j] = b4[j] + sum_{k<256} h3[r][k] W4[k*32+j]  (linear); k-split x4
  auto fwd_l4 = [&]() {
    int item = tid & 127;
    int r = item >> 5, j = item & 31, kg = tid >> 7;
    const float* hr = &h3[0][0] + r * 256;
    float a = 0.f;
#pragma unroll 4
    for (int k = kg * 64; k < kg * 64 + 64; k += 4) {
      float4 h4 = *reinterpret_cast<const float4*>(hr + k);
      a += h4.x * pW4[(k    ) * 32 + j];
      a += h4.y * pW4[(k + 1) * 32 + j];
      a += h4.z * pW4[(k + 2) * 32 + j];
      a += h4.w * pW4[(k + 3) * 32 + j];
    }
    tmp4[kg][r][j] = a;
    __syncthreads();
    if (tid < 128) {
      int r2 = tid >> 5, j2 = tid & 31;
      wv[r2][j2] = tmp4[0][r2][j2] + tmp4[1][r2][j2] + tmp4[2][r2][j2] +
                   tmp4[3][r2][j2] + pb4[j2];
    }
  };

  // RNN cell fwd: hNew = tanh(cat(x,w)@Wih^T + bih + hOld@Whh^T + bhh)
  auto rnn_fwd = [&]() {
    if (tid < 128) {
      int r = tid >> 5, i = tid & 31;
      float a = pbih[i] + pbhh[i];
#pragma unroll
      for (int c = 0; c < IND; ++c) a += xs[r][c] * WihT[c * 32 + i];
#pragma unroll 8
      for (int c = 0; c < SU; ++c) a += wv[r][c] * WihT[(13 + c) * 32 + i];
#pragma unroll 8
      for (int j = 0; j < HID; ++j) a += hOld[r][j] * WhhT[j * 32 + i];
      hNew[r][i] = tanhf(a);
    }
  };

  // wide bwd (OUT=256) with UNtransposed W[256][K]:
  // dout_mask[r][j] = (dout_mask[r][j] > 0) * sum_k din[r][k] W[j*K+k]
  auto bwd_wide = [&](const float* __restrict__ W, int K,
                      const float* din, float* dout_mask) {
    int j = tid & 255, rA = tid >> 8, rB = rA + 2;
    const float* dA = din + rA * K;
    const float* dB = din + rB * K;
    const float* Wr = W + j * K;
    float a0 = 0.f, a1 = 0.f;
#pragma unroll 4
    for (int k = 0; k < K; k += 4) {
      float4 w4 = *reinterpret_cast<const float4*>(Wr + k);
      float4 gA = *reinterpret_cast<const float4*>(dA + k);
      float4 gB = *reinterpret_cast<const float4*>(dB + k);
      a0 += w4.x * gA.x + w4.y * gA.y + w4.z * gA.z + w4.w * gA.w;
      a1 += w4.x * gB.x + w4.y * gB.y + w4.z * gB.z + w4.w * gB.w;
    }
    float mA = (dout_mask[rA * 256 + j] > 0.f) ? a0 : 0.f;
    float mB = (dout_mask[rB * 256 + j] > 0.f) ? a1 : 0.f;
    dout_mask[rA * 256 + j] = mA;
    dout_mask[rB * 256 + j] = mB;
  };

  // dh1[r][j] = mask(h1) * sum_{k<256} dh2[r][k] W2[j*256+k]; k-split x4, in-place on h1
  auto bwd_dh1 = [&]() {
    int j = tid & 127, kg = tid >> 7;
    const float* Wr = pW2 + j * 256 + kg * 64;
    const float* g0 = &h2[0][0] + kg * 64;
    const float* g1 = &h2[1][0] + kg * 64;
    const float* g2 = &h2[2][0] + kg * 64;
    const float* g3 = &h2[3][0] + kg * 64;
    float a0 = 0.f, a1 = 0.f, a2 = 0.f, a3 = 0.f;
#pragma unroll 4
    for (int k = 0; k < 64; k += 4) {
      float4 w4 = *reinterpret_cast<const float4*>(Wr + k);
      float4 q0 = *reinterpret_cast<const float4*>(g0 + k);
      float4 q1 = *reinterpret_cast<const float4*>(g1 + k);
      float4 q2 = *reinterpret_cast<const float4*>(g2 + k);
      float4 q3 = *reinterpret_cast<const float4*>(g3 + k);
      a0 += w4.x * q0.x + w4.y * q0.y + w4.z * q0.z + w4.w * q0.w;
      a1 += w4.x * q1.x + w4.y * q1.y + w4.z * q1.z + w4.w * q1.w;
      a2 += w4.x * q2.x + w4.y * q2.y + w4.z * q2.z + w4.w * q2.w;
      a3 += w4.x * q3.x + w4.y * q3.y + w4.z * q3.z + w4.w * q3.w;
    }
    tmp4[kg][0][j] = a0; tmp4[kg][1][j] = a1;
    tmp4[kg][2][j] = a2; tmp4[kg][3][j] = a3;
    __syncthreads();
    int r = tid >> 7, j2 = tid & 127;
    float v = tmp4[0][r][j2] + tmp4[1][r][j2] + tmp4[2][r][j2] + tmp4[3][r][j2];
    h1[r][j2] = (h1[r][j2] > 0.f) ? v : 0.f;
  };

  // ds[r][k] = sum_{j<128} dh1[r][j] W1[k*128+j]; j-split x4
  auto bwd_ds = [&]() {
    int k = tid & 31, r = (tid >> 5) & 3, jg = tid >> 7;
    const float* gr = &h1[0][0] + r * 128 + jg * 32;
    const float* Wr = pW1 + k * 128 + jg * 32;
    float a = 0.f;
#pragma unroll
    for (int j = 0; j < 32; j += 4) {
      float4 g4 = *reinterpret_cast<const float4*>(gr + j);
      float4 w4 = *reinterpret_cast<const float4*>(Wr + j);
      a += g4.x * w4.x + g4.y * w4.y + g4.z * w4.z + g4.w * w4.w;
    }
    tmp4[jg][r][k] = a;
    __syncthreads();
    if (tid < 128) {
      int r2 = tid >> 5, k2 = tid & 31;
      dsb[r2][k2] = tmp4[0][r2][k2] + tmp4[1][r2][k2] + tmp4[2][r2][k2] + tmp4[3][r2][k2];
    }
  };

  // publish column partial-sums of current story + tag
  auto publish = [&](int pslot, unsigned tagval) {
    __syncthreads();
    if (tid < SU) {
      part[(size_t)pslot * NB * SU + (size_t)bid * SU + tid] =
          s[0][tid] + s[1][tid] + s[2][tid] + s[3][tid];
    }
    __threadfence();
    __syncthreads();
    if (tid == 0)
      __hip_atomic_store(&tags[pslot * NB + bid], tagval, __ATOMIC_RELEASE,
                         __HIP_MEMORY_SCOPE_AGENT);
  };

  // ---- init: story = 0, publish initial partials (tag 1, slot 0)
  if (tid < 128) { int r = tid >> 5, c = tid & 31; s[r][c] = 0.f; }
  publish(0, 1u);

  // ---- outer timesteps
  for (int ts = 0; ts < TSTEPS; ++ts) {
    if (tid < 4 * IND) {
      int r = tid / IND, c = tid % IND;
      xs[r][c] = X[(size_t)ts * BATCH * IND + (size_t)(row0 + r) * IND + c];
    }
    if (tid >= 64 && tid < 64 + 4 * OD) {
      int q = tid - 64; int r = q / OD, c = q % OD;
      ysd[r][c] = Y[(size_t)ts * BATCH * OD + (size_t)(row0 + r) * OD + c];
    }
    if (tid >= 128 && tid < 256) {
      int q = tid - 128; int r = q >> 5, c = q & 31;
      mAd[r][c] = 0.f; vAd[r][c] = 0.f; hOld[r][c] = 0.f;
    }
    float pb1t = 1.f, pb2t = 1.f;

    for (int it = 0; it < ITERS; ++it) {
      const int gi = ts * ITERS + it;
      const int p = gi & 1;
      pb1t *= AB1; pb2t *= AB2;

      // wait for all blocks' partials for this iteration (2-deep pipeline)
      if (tid < NB) spin_ge(&tags[p * NB + tid], (unsigned)(gi + 1));
      __syncthreads();
      __threadfence();

      // mu reduction (every block, redundantly)
      if (tid < 256) {
        int c = tid & 31, grp = tid >> 5;
        const float* P = part + (size_t)p * NB * SU;
        float sum = 0.f;
#pragma unroll 8
        for (int b2 = grp * 32; b2 < grp * 32 + 32; ++b2) sum += P[b2 * SU + c];
        red[grp][c] = sum;
      }
      __syncthreads();
      if (tid < SU) {
        float sum = 0.f;
#pragma unroll
        for (int g2 = 0; g2 < 8; ++g2) sum += red[g2][tid];
        mu[tid] = sum * (1.f / 1024.f);
      }
      __syncthreads();

      // ---- forward
      fwd_l1(); __syncthreads();
      fwd_wide(pW2, pb2, &h1[0][0], 128, &h2[0][0]); __syncthreads();
      fwd_wide(pW3, pb3, &h2[0][0], 256, &h3[0][0]); __syncthreads();
      fwd_l4(); __syncthreads();
      rnn_fwd(); __syncthreads();

      if (tid < 36) {  // decoder + d(err)/d(adec)
        int r = tid / OD, d = tid % OD;
        float adec = pbd[d];
#pragma unroll
        for (int i = 0; i < HID; ++i) adec += hNew[r][i] * pWd[i * OD + d];
        float pr = fmaxf(adec, 0.f);
        dadec[r][d] = (adec > 0.f) ? (2.f / 1024.f) * (pr - ysd[r][d]) : 0.f;
      }
      __syncthreads();

      if (tid < 128) {  // d h_new -> da (through tanh)
        int r = tid >> 5, i = tid & 31;
        float t1 = 0.f;
#pragma unroll
        for (int d = 0; d < OD; ++d) t1 += dadec[r][d] * pWd[i * OD + d];
        float hn = hNew[r][i];
        da[r][i] = t1 * (1.f - hn * hn);
      }
      __syncthreads();

      if (tid < 128) {  // dw_k = sum_i da_i Wih[i][13+k]
        int r = tid >> 5, k = tid & 31;
        float t2 = 0.f;
#pragma unroll 8
        for (int i = 0; i < HID; ++i) t2 += da[r][i] * WihT[(13 + k) * 32 + i];
        dwb[r][k] = t2;
      }
      __syncthreads();

      // ---- backward through hypernet (in-place with relu masks)
      bwd_wide(pW4, 32, &dwb[0][0], &h3[0][0]); __syncthreads();
      bwd_wide(pW3, 256, &h3[0][0], &h2[0][0]); __syncthreads();
      bwd_dh1(); __syncthreads();
      bwd_ds(); __syncthreads();

      // ---- Adam update + hidden carry
      if (tid < 128) {
        int r = tid >> 5, c = tid & 31;
        float sv = s[r][c];
        float g = dsb[r][c] + (sv - mu[c]) * (2.f / 1023.f) + sv * (2e-4f / 1024.f);
        float m2 = AB1 * mAd[r][c] + (1.f - AB1) * g;
        float v2 = AB2 * vAd[r][c] + (1.f - AB2) * g * g;
        mAd[r][c] = m2; vAd[r][c] = v2;
        float mh = m2 / (1.f - pb1t);
        float vh = v2 / (1.f - pb2t);
        s[r][c] = sv - LR * mh / (sqrtf(vh) + AEPS);
        hOld[r][c] = hNew[r][c];
      }

      publish((gi + 1) & 1, (unsigned)(gi + 2));
    }
  }

  // ---- final evaluation: w = hyper(final story) (story partials already
  // published with tag 401 into slot 0)
  fwd_l1(); __syncthreads();
  fwd_wide(pW2, pb2, &h1[0][0], 128, &h2[0][0]); __syncthreads();
  fwd_wide(pW3, pb3, &h2[0][0], 256, &h3[0][0]); __syncthreads();
  fwd_l4(); __syncthreads();

  if (tid < 128) { int r = tid >> 5, i = tid & 31; hOld[r][i] = 0.f; }
  __syncthreads();

  float errACC = 0.f;
  for (int t2 = 0; t2 < TSTEPS; ++t2) {
    if (tid < 4 * IND) {
      int r = tid / IND, c = tid % IND;
      xs[r][c] = X[(size_t)t2 * BATCH * IND + (size_t)(row0 + r) * IND + c];
    }
    __syncthreads();
    rnn_fwd(); __syncthreads();
    if (tid < 36) {
      int r = tid / OD, d = tid % OD;
      float adec = pbd[d];
#pragma unroll
      for (int i = 0; i < HID; ++i) adec += hNew[r][i] * pWd[i * OD + d];
      float pr = fmaxf(adec, 0.f);
      float e = pr - Y[(size_t)t2 * BATCH * OD + (size_t)(row0 + r) * OD + d];
      errACC += e * e;
    }
    if (tid < 128) { int r = tid >> 5, i = tid & 31; hOld[r][i] = hNew[r][i]; }
    __syncthreads();
  }

  if (tid < 36) (&red[0][0])[tid] = errACC;
  __syncthreads();
  if (tid == 0) {
    float sum = 0.f;
    for (int q = 0; q < 36; ++q) sum += (&red[0][0])[q];
    errp[bid] = sum;
    __threadfence();
    __hip_atomic_store(&tags2[bid], 1u, __ATOMIC_RELEASE, __HIP_MEMORY_SCOPE_AGENT);
  }

  // block 0 produces the 33 outputs
  if (bid == 0) {
    if (tid < NB) {
      spin_ge(&tags2[tid], 1u);
      spin_ge(&tags[0 * NB + tid], 401u);
    }
    __syncthreads();
    __threadfence();
    if (tid == 0) {
      float sum = 0.f;
      for (int b = 0; b < NB; ++b) sum += errp[b];
      out[0] = sum * (1.f / 1024.f);
    }
    if (tid >= 64 && tid < 96) {
      int c = tid - 64;
      float sum = 0.f;
      for (int b = 0; b < NB; ++b) sum += part[(size_t)b * SU + c];
      out[1 + c] = sum * (1.f / 1024.f);
    }
  }
}

extern "C" void kernel_launch(void* const* d_in, const int* in_sizes, int n_in,
                              void* d_out, int out_size, void* d_ws, size_t ws_size,
                              hipStream_t stream) {
  (void)in_sizes; (void)n_in; (void)out_size;
  if (ws_size < WS_NEEDED) return;

  const float* X   = (const float*)d_in[0];
  const float* Y   = (const float*)d_in[1];
  const float* W1  = (const float*)d_in[2];
  const float* b1  = (const float*)d_in[3];
  const float* W2  = (const float*)d_in[4];
  const float* b2  = (const float*)d_in[5];
  const float* W3  = (const float*)d_in[6];
  const float* b3  = (const float*)d_in[7];
  const float* W4  = (const float*)d_in[8];
  const float* b4  = (const float*)d_in[9];
  const float* Wih = (const float*)d_in[10];
  const float* Whh = (const float*)d_in[11];
  const float* bih = (const float*)d_in[12];
  const float* bhh = (const float*)d_in[13];
  const float* Wd  = (const float*)d_in[14];
  const float* bd  = (const float*)d_in[15];

  // zero the tag regions (tags + tags2 = first 3072 bytes)
  hipMemsetAsync(d_ws, 0, 3072, stream);
  prep_kernel<<<8, 256, 0, stream>>>(Wih, Whh, (char*)d_ws);
  emb_kernel<<<NB, NT, 0, stream>>>(X, Y, W1, b1, W2, b2, W3, b3, W4, b4,
                                    Wih, Whh, bih, bhh, Wd, bd,
                                    (char*)d_ws, (float*)d_out);
}

// Round 5
// 35194.196 us; speedup vs baseline: 1.3788x; 1.3788x over previous
//
#include <hip/hip_runtime.h>

#define NB 256
#define NT 512

constexpr int BATCH = 1024;
constexpr int TSTEPS = 20;
constexpr int IND = 13;
constexpr int OD = 9;
constexpr int SU = 32;
constexpr int HID = 32;
constexpr int ITERS = 20;
constexpr float LR = 0.1f;
constexpr float AB1 = 0.9f;
constexpr float AB2 = 0.999f;
constexpr float AEPS = 1e-8f;

// bounded-spin cap: expected waits are ~µs; this is seconds. On trip, the
// block proceeds -> run terminates with wrong output instead of hanging.
constexpr unsigned SPIN_CAP = 1u << 27;

// workspace byte offsets
constexpr size_t OFF_TAGS  = 0;        // u32 [2][NB]   (zeroed by memset)
constexpr size_t OFF_TAGS2 = 2048;     // u32 [NB]      (zeroed by memset)
constexpr size_t OFF_ERRP  = 3072;     // f32 [NB]
constexpr size_t OFF_PART  = 4096;     // f32 [2][NB][SU]        -> 69632
constexpr size_t OFF_WIHT  = 69632;    // f32 [45][32]           -> 75392
constexpr size_t OFF_WHHT  = 75392;    // f32 [32][32]           -> 79488
constexpr size_t OFF_W2T   = 79488;    // f32 [256][128]         -> 210560
constexpr size_t OFF_W3T   = 210560;   // f32 [256][256]         -> 472704
constexpr size_t OFF_W4T   = 472704;   // f32 [32][256]          -> 505472
constexpr size_t WS_NEEDED = 505472;

__device__ __forceinline__ void fma4(float4& a, const float4 w, const float h) {
  a.x += w.x * h; a.y += w.y * h; a.z += w.z * h; a.w += w.w * h;
}
__device__ __forceinline__ float dot4(const float4 a, const float4 b) {
  return a.x * b.x + a.y * b.y + a.z * b.z + a.w * b.w;
}

__global__ void prep_kernel(const float* __restrict__ Wih,
                            const float* __restrict__ Whh,
                            const float* __restrict__ W2,
                            const float* __restrict__ W3,
                            const float* __restrict__ W4,
                            char* __restrict__ ws) {
  float* WihT = reinterpret_cast<float*>(ws + OFF_WIHT);
  float* WhhT = reinterpret_cast<float*>(ws + OFF_WHHT);
  float* W2T  = reinterpret_cast<float*>(ws + OFF_W2T);
  float* W3T  = reinterpret_cast<float*>(ws + OFF_W3T);
  float* W4T  = reinterpret_cast<float*>(ws + OFF_W4T);
  int tid = blockIdx.x * blockDim.x + threadIdx.x;
  int nt = gridDim.x * blockDim.x;
  for (int idx = tid; idx < 32 * 45; idx += nt) {
    int i = idx / 45, c = idx % 45;
    WihT[c * 32 + i] = Wih[idx];
  }
  for (int idx = tid; idx < 32 * 32; idx += nt) {
    int i = idx >> 5, j = idx & 31;
    WhhT[j * 32 + i] = Whh[idx];
  }
  // W2 [128][256] -> W2T [256][128]
  for (int idx = tid; idx < 256 * 128; idx += nt) {
    int k = idx >> 7, j = idx & 127;
    W2T[idx] = W2[j * 256 + k];
  }
  // W3 [256][256] -> W3T [256][256]
  for (int idx = tid; idx < 256 * 256; idx += nt) {
    int k = idx >> 8, j = idx & 255;
    W3T[idx] = W3[j * 256 + k];
  }
  // W4 [256][32] -> W4T [32][256]
  for (int idx = tid; idx < 32 * 256; idx += nt) {
    int k = idx >> 8, j = idx & 255;
    W4T[idx] = W4[j * 32 + k];
  }
}

__global__ __launch_bounds__(NT) void emb_kernel(
    const float* __restrict__ X, const float* __restrict__ Y,
    const float* __restrict__ pW1, const float* __restrict__ pb1,
    const float* __restrict__ pW2, const float* __restrict__ pb2,
    const float* __restrict__ pW3, const float* __restrict__ pb3,
    const float* __restrict__ pW4, const float* __restrict__ pb4,
    const float* __restrict__ pWih, const float* __restrict__ pWhh,
    const float* __restrict__ pbih, const float* __restrict__ pbhh,
    const float* __restrict__ pWd, const float* __restrict__ pbd,
    char* __restrict__ ws, float* __restrict__ out) {
  const int tid = threadIdx.x;
  const int bid = blockIdx.x;
  const int row0 = bid * 4;

  unsigned* tags  = reinterpret_cast<unsigned*>(ws + OFF_TAGS);   // [2][NB]
  unsigned* tags2 = reinterpret_cast<unsigned*>(ws + OFF_TAGS2);  // [NB]
  float* errp = reinterpret_cast<float*>(ws + OFF_ERRP);          // [NB]
  float* part = reinterpret_cast<float*>(ws + OFF_PART);          // [2][NB][SU]
  const float* WihT = reinterpret_cast<const float*>(ws + OFF_WIHT);
  const float* WhhT = reinterpret_cast<const float*>(ws + OFF_WHHT);
  const float* W2T  = reinterpret_cast<const float*>(ws + OFF_W2T);
  const float* W3T  = reinterpret_cast<const float*>(ws + OFF_W3T);
  const float* W4T  = reinterpret_cast<const float*>(ws + OFF_W4T);

  __shared__ alignas(16) float s[4][SU];
  __shared__ alignas(16) float mAd[4][SU];
  __shared__ alignas(16) float vAd[4][SU];
  __shared__ alignas(16) float hOld[4][HID];
  __shared__ alignas(16) float hNew[4][HID];
  __shared__ alignas(16) float h1[4][128];
  __shared__ alignas(16) float h2[4][256];
  __shared__ alignas(16) float h3[4][256];
  __shared__ alignas(16) float wv[4][SU];
  __shared__ alignas(16) float da[4][HID];
  __shared__ alignas(16) float dwb[4][SU];
  __shared__ alignas(16) float dsb[4][SU];
  __shared__ alignas(16) float red2[8192];   // 32 KB k-split partial buffer
  __shared__ float xs[4][IND];
  __shared__ float ysd[4][OD];
  __shared__ float dadec[4][OD];
  __shared__ float mu[SU];
  __shared__ float red[8][SU];

  // bounded spin until *tagp >= tgt (returns regardless after SPIN_CAP polls)
  auto spin_ge = [&](unsigned* tagp, unsigned tgt) {
    unsigned n = 0;
    while (__hip_atomic_load(tagp, __ATOMIC_RELAXED,
                             __HIP_MEMORY_SCOPE_AGENT) < tgt) {
      __builtin_amdgcn_s_sleep(1);
      if (++n >= SPIN_CAP) break;
    }
  };

  // ---- layer routines. Pattern: k-split compute (float4 weight loads,
  // each load feeds all 4 rows = 16 FMA/load) -> barrier -> reduce.

  // L1 fwd: h1[4][128] = relu(s[4][32] @ W1[32][128] + b1)
  auto fwd_l1 = [&]() {
    if (tid < 256) {
      int j0 = (tid & 31) * 4, kg = tid >> 5;  // 8 kg x 4 k
      float4 a0 = {0,0,0,0}, a1 = a0, a2 = a0, a3 = a0;
#pragma unroll
      for (int q = 0; q < 4; ++q) {
        int k = kg * 4 + q;
        float4 w = *reinterpret_cast<const float4*>(pW1 + k * 128 + j0);
        fma4(a0, w, s[0][k]); fma4(a1, w, s[1][k]);
        fma4(a2, w, s[2][k]); fma4(a3, w, s[3][k]);
      }
      *reinterpret_cast<float4*>(&red2[(kg * 4 + 0) * 128 + j0]) = a0;
      *reinterpret_cast<float4*>(&red2[(kg * 4 + 1) * 128 + j0]) = a1;
      *reinterpret_cast<float4*>(&red2[(kg * 4 + 2) * 128 + j0]) = a2;
      *reinterpret_cast<float4*>(&red2[(kg * 4 + 3) * 128 + j0]) = a3;
    }
    __syncthreads();
    int r = tid >> 7, j = tid & 127;
    float sum = pb1[j];
#pragma unroll
    for (int g = 0; g < 8; ++g) sum += red2[(g * 4 + r) * 128 + j];
    h1[r][j] = fmaxf(sum, 0.f);
  };

  // wide fwd: hout[4][256] = relu(hin[4][K] @ W[K][256] + bias), K in {128,256}
  auto fwd_wide = [&](const float* __restrict__ W, const float* __restrict__ bias,
                      const float* hin, int K, float* hout) {
    {
      int j0 = (tid & 63) * 4, kg = tid >> 6;  // 8 kg
      int kn = K >> 3;                          // 16 or 32
      float4 a0 = {0,0,0,0}, a1 = a0, a2 = a0, a3 = a0;
#pragma unroll 8
      for (int q = 0; q < kn; ++q) {
        int k = kg * kn + q;
        float4 w = *reinterpret_cast<const float4*>(W + k * 256 + j0);
        fma4(a0, w, hin[0 * K + k]); fma4(a1, w, hin[1 * K + k]);
        fma4(a2, w, hin[2 * K + k]); fma4(a3, w, hin[3 * K + k]);
      }
      *reinterpret_cast<float4*>(&red2[(kg * 4 + 0) * 256 + j0]) = a0;
      *reinterpret_cast<float4*>(&red2[(kg * 4 + 1) * 256 + j0]) = a1;
      *reinterpret_cast<float4*>(&red2[(kg * 4 + 2) * 256 + j0]) = a2;
      *reinterpret_cast<float4*>(&red2[(kg * 4 + 3) * 256 + j0]) = a3;
    }
    __syncthreads();
    int o = tid * 2, r = o >> 8, j = o & 255;
    float s0 = bias[j], s1 = bias[j + 1];
#pragma unroll
    for (int g = 0; g < 8; ++g) {
      float2 p = *reinterpret_cast<const float2*>(&red2[(g * 4 + r) * 256 + j]);
      s0 += p.x; s1 += p.y;
    }
    hout[r * 256 + j]     = fmaxf(s0, 0.f);
    hout[r * 256 + j + 1] = fmaxf(s1, 0.f);
  };

  // L4 fwd: wv[4][32] = h3[4][256] @ W4[256][32] + b4 (linear)
  auto fwd_l4 = [&]() {
    if (tid < 128) {
      int j0 = (tid & 7) * 4, kg = tid >> 3;  // 16 kg x 16 k
      float4 a0 = {0,0,0,0}, a1 = a0, a2 = a0, a3 = a0;
#pragma unroll 8
      for (int q = 0; q < 16; ++q) {
        int k = kg * 16 + q;
        float4 w = *reinterpret_cast<const float4*>(pW4 + k * 32 + j0);
        fma4(a0, w, h3[0][k]); fma4(a1, w, h3[1][k]);
        fma4(a2, w, h3[2][k]); fma4(a3, w, h3[3][k]);
      }
      *reinterpret_cast<float4*>(&red2[(kg * 4 + 0) * 32 + j0]) = a0;
      *reinterpret_cast<float4*>(&red2[(kg * 4 + 1) * 32 + j0]) = a1;
      *reinterpret_cast<float4*>(&red2[(kg * 4 + 2) * 32 + j0]) = a2;
      *reinterpret_cast<float4*>(&red2[(kg * 4 + 3) * 32 + j0]) = a3;
    }
    __syncthreads();
    if (tid < 128) {
      int r = tid >> 5, j = tid & 31;
      float sum = pb4[j];
#pragma unroll
      for (int g = 0; g < 16; ++g) sum += red2[(g * 4 + r) * 32 + j];
      wv[r][j] = sum;
    }
  };

  // RNN cell fwd: hNew = tanh(cat(x,w)@Wih^T + bih + hOld@Whh^T + bhh)
  auto rnn_fwd = [&]() {
    if (tid < 128) {
      int r = tid >> 5, i = tid & 31;
      float a = pbih[i] + pbhh[i];
#pragma unroll
      for (int c = 0; c < IND; ++c) a += xs[r][c] * WihT[c * 32 + i];
#pragma unroll 8
      for (int c = 0; c < SU; ++c) a += wv[r][c] * WihT[(13 + c) * 32 + i];
#pragma unroll 8
      for (int j = 0; j < HID; ++j) a += hOld[r][j] * WhhT[j * 32 + i];
      hNew[r][i] = tanhf(a);
    }
  };

  // bwd through a 256-wide output with TRANSPOSED weights WT[Kd][256]:
  // dmask[r][j] = (dmask[r][j] > 0) * sum_k din[r*Kd+k] WT[k*256+j]
  auto bwdT256 = [&](const float* __restrict__ WT, const float* din, int Kd,
                     float* dmask) {
    {
      int j0 = (tid & 63) * 4, kg = tid >> 6;  // 8 kg
      int kn = Kd >> 3;                         // 4 or 32
      float4 a0 = {0,0,0,0}, a1 = a0, a2 = a0, a3 = a0;
#pragma unroll 4
      for (int q = 0; q < kn; ++q) {
        int k = kg * kn + q;
        float4 w = *reinterpret_cast<const float4*>(WT + k * 256 + j0);
        fma4(a0, w, din[0 * Kd + k]); fma4(a1, w, din[1 * Kd + k]);
        fma4(a2, w, din[2 * Kd + k]); fma4(a3, w, din[3 * Kd + k]);
      }
      *reinterpret_cast<float4*>(&red2[(kg * 4 + 0) * 256 + j0]) = a0;
      *reinterpret_cast<float4*>(&red2[(kg * 4 + 1) * 256 + j0]) = a1;
      *reinterpret_cast<float4*>(&red2[(kg * 4 + 2) * 256 + j0]) = a2;
      *reinterpret_cast<float4*>(&red2[(kg * 4 + 3) * 256 + j0]) = a3;
    }
    __syncthreads();
    int o = tid * 2, r = o >> 8, j = o & 255;
    float s0 = 0.f, s1 = 0.f;
#pragma unroll
    for (int g = 0; g < 8; ++g) {
      float2 p = *reinterpret_cast<const float2*>(&red2[(g * 4 + r) * 256 + j]);
      s0 += p.x; s1 += p.y;
    }
    float m0 = dmask[r * 256 + j], m1 = dmask[r * 256 + j + 1];
    dmask[r * 256 + j]     = (m0 > 0.f) ? s0 : 0.f;
    dmask[r * 256 + j + 1] = (m1 > 0.f) ? s1 : 0.f;
  };

  // dh1[r][j<128] = mask(h1) * sum_{k<256} dh2[r][k] W2T[k*128+j]
  auto bwd_dh1 = [&]() {
    {
      int j0 = (tid & 31) * 4, kg = tid >> 5;  // 16 kg x 16 k
      float4 a0 = {0,0,0,0}, a1 = a0, a2 = a0, a3 = a0;
#pragma unroll 8
      for (int q = 0; q < 16; ++q) {
        int k = kg * 16 + q;
        float4 w = *reinterpret_cast<const float4*>(W2T + k * 128 + j0);
        fma4(a0, w, h2[0][k]); fma4(a1, w, h2[1][k]);
        fma4(a2, w, h2[2][k]); fma4(a3, w, h2[3][k]);
      }
      *reinterpret_cast<float4*>(&red2[(kg * 4 + 0) * 128 + j0]) = a0;
      *reinterpret_cast<float4*>(&red2[(kg * 4 + 1) * 128 + j0]) = a1;
      *reinterpret_cast<float4*>(&red2[(kg * 4 + 2) * 128 + j0]) = a2;
      *reinterpret_cast<float4*>(&red2[(kg * 4 + 3) * 128 + j0]) = a3;
    }
    __syncthreads();
    int r = tid >> 7, j = tid & 127;
    float sum = 0.f;
#pragma unroll
    for (int g = 0; g < 16; ++g) sum += red2[(g * 4 + r) * 128 + j];
    h1[r][j] = (h1[r][j] > 0.f) ? sum : 0.f;
  };

  // ds[r][k<32] = sum_{j<128} dh1[r][j] W1[k*128+j]
  auto bwd_ds = [&]() {
    if (tid < 256) {
      int k0 = (tid & 7) * 4, jg = (tid >> 3) & 31;
      int j0 = jg * 4;
      float4 g0 = *reinterpret_cast<const float4*>(&h1[0][j0]);
      float4 g1 = *reinterpret_cast<const float4*>(&h1[1][j0]);
      float4 g2 = *reinterpret_cast<const float4*>(&h1[2][j0]);
      float4 g3 = *reinterpret_cast<const float4*>(&h1[3][j0]);
      float4 a0, a1, a2, a3;
      float* A0 = &a0.x; float* A1 = &a1.x; float* A2 = &a2.x; float* A3 = &a3.x;
#pragma unroll
      for (int q = 0; q < 4; ++q) {
        int k = k0 + q;
        float4 w = *reinterpret_cast<const float4*>(pW1 + k * 128 + j0);
        A0[q] = dot4(w, g0); A1[q] = dot4(w, g1);
        A2[q] = dot4(w, g2); A3[q] = dot4(w, g3);
      }
      *reinterpret_cast<float4*>(&red2[jg * 128 + 0 * 32 + k0]) = a0;
      *reinterpret_cast<float4*>(&red2[jg * 128 + 1 * 32 + k0]) = a1;
      *reinterpret_cast<float4*>(&red2[jg * 128 + 2 * 32 + k0]) = a2;
      *reinterpret_cast<float4*>(&red2[jg * 128 + 3 * 32 + k0]) = a3;
    }
    __syncthreads();
    if (tid < 128) {
      int r = tid >> 5, k = tid & 31;
      float sum = 0.f;
#pragma unroll
      for (int g = 0; g < 32; ++g) sum += red2[g * 128 + r * 32 + k];
      dsb[r][k] = sum;
    }
  };

  // publish column partial-sums of current story + tag
  auto publish = [&](int pslot, unsigned tagval) {
    __syncthreads();
    if (tid < SU) {
      part[(size_t)pslot * NB * SU + (size_t)bid * SU + tid] =
          s[0][tid] + s[1][tid] + s[2][tid] + s[3][tid];
    }
    __threadfence();
    __syncthreads();
    if (tid == 0)
      __hip_atomic_store(&tags[pslot * NB + bid], tagval, __ATOMIC_RELEASE,
                         __HIP_MEMORY_SCOPE_AGENT);
  };

  // ---- init: story = 0, publish initial partials (tag 1, slot 0)
  if (tid < 128) { int r = tid >> 5, c = tid & 31; s[r][c] = 0.f; }
  publish(0, 1u);

  // ---- outer timesteps
  for (int ts = 0; ts < TSTEPS; ++ts) {
    if (tid < 4 * IND) {
      int r = tid / IND, c = tid % IND;
      xs[r][c] = X[(size_t)ts * BATCH * IND + (size_t)(row0 + r) * IND + c];
    }
    if (tid >= 64 && tid < 64 + 4 * OD) {
      int q = tid - 64; int r = q / OD, c = q % OD;
      ysd[r][c] = Y[(size_t)ts * BATCH * OD + (size_t)(row0 + r) * OD + c];
    }
    if (tid >= 128 && tid < 256) {
      int q = tid - 128; int r = q >> 5, c = q & 31;
      mAd[r][c] = 0.f; vAd[r][c] = 0.f; hOld[r][c] = 0.f;
    }
    float pb1t = 1.f, pb2t = 1.f;

    for (int it = 0; it < ITERS; ++it) {
      const int gi = ts * ITERS + it;
      const int p = gi & 1;
      pb1t *= AB1; pb2t *= AB2;

      // wait for all blocks' partials for this iteration (2-deep pipeline)
      if (tid < NB) spin_ge(&tags[p * NB + tid], (unsigned)(gi + 1));
      __syncthreads();
      __threadfence();

      // mu reduction (every block, redundantly)
      if (tid < 256) {
        int c = tid & 31, grp = tid >> 5;
        const float* P = part + (size_t)p * NB * SU;
        float sum = 0.f;
#pragma unroll 8
        for (int b2 = grp * 32; b2 < grp * 32 + 32; ++b2) sum += P[b2 * SU + c];
        red[grp][c] = sum;
      }
      __syncthreads();
      if (tid < SU) {
        float sum = 0.f;
#pragma unroll
        for (int g2 = 0; g2 < 8; ++g2) sum += red[g2][tid];
        mu[tid] = sum * (1.f / 1024.f);
      }
      __syncthreads();

      // ---- forward
      fwd_l1(); __syncthreads();
      fwd_wide(pW2, pb2, &h1[0][0], 128, &h2[0][0]); __syncthreads();
      fwd_wide(pW3, pb3, &h2[0][0], 256, &h3[0][0]); __syncthreads();
      fwd_l4(); __syncthreads();
      rnn_fwd(); __syncthreads();

      if (tid < 36) {  // decoder + d(err)/d(adec)
        int r = tid / OD, d = tid % OD;
        float adec = pbd[d];
#pragma unroll
        for (int i = 0; i < HID; ++i) adec += hNew[r][i] * pWd[i * OD + d];
        float pr = fmaxf(adec, 0.f);
        dadec[r][d] = (adec > 0.f) ? (2.f / 1024.f) * (pr - ysd[r][d]) : 0.f;
      }
      __syncthreads();

      if (tid < 128) {  // d h_new -> da (through tanh)
        int r = tid >> 5, i = tid & 31;
        float t1 = 0.f;
#pragma unroll
        for (int d = 0; d < OD; ++d) t1 += dadec[r][d] * pWd[i * OD + d];
        float hn = hNew[r][i];
        da[r][i] = t1 * (1.f - hn * hn);
      }
      __syncthreads();

      if (tid < 128) {  // dw_k = sum_i da_i Wih[i][13+k]
        int r = tid >> 5, k = tid & 31;
        float t2 = 0.f;
#pragma unroll 8
        for (int i = 0; i < HID; ++i) t2 += da[r][i] * WihT[(13 + k) * 32 + i];
        dwb[r][k] = t2;
      }
      __syncthreads();

      // ---- backward through hypernet (in-place with relu masks)
      bwdT256(W4T, &dwb[0][0], 32, &h3[0][0]); __syncthreads();
      bwdT256(W3T, &h3[0][0], 256, &h2[0][0]); __syncthreads();
      bwd_dh1(); __syncthreads();
      bwd_ds(); __syncthreads();

      // ---- Adam update + hidden carry
      if (tid < 128) {
        int r = tid >> 5, c = tid & 31;
        float sv = s[r][c];
        float g = dsb[r][c] + (sv - mu[c]) * (2.f / 1023.f) + sv * (2e-4f / 1024.f);
        float m2 = AB1 * mAd[r][c] + (1.f - AB1) * g;
        float v2 = AB2 * vAd[r][c] + (1.f - AB2) * g * g;
        mAd[r][c] = m2; vAd[r][c] = v2;
        float mh = m2 / (1.f - pb1t);
        float vh = v2 / (1.f - pb2t);
        s[r][c] = sv - LR * mh / (sqrtf(vh) + AEPS);
        hOld[r][c] = hNew[r][c];
      }

      publish((gi + 1) & 1, (unsigned)(gi + 2));
    }
  }

  // ---- final evaluation: w = hyper(final story) (story partials already
  // published with tag 401 into slot 0)
  fwd_l1(); __syncthreads();
  fwd_wide(pW2, pb2, &h1[0][0], 128, &h2[0][0]); __syncthreads();
  fwd_wide(pW3, pb3, &h2[0][0], 256, &h3[0][0]); __syncthreads();
  fwd_l4(); __syncthreads();

  if (tid < 128) { int r = tid >> 5, i = tid & 31; hOld[r][i] = 0.f; }
  __syncthreads();

  float errACC = 0.f;
  for (int t2 = 0; t2 < TSTEPS; ++t2) {
    if (tid < 4 * IND) {
      int r = tid / IND, c = tid % IND;
      xs[r][c] = X[(size_t)t2 * BATCH * IND + (size_t)(row0 + r) * IND + c];
    }
    __syncthreads();
    rnn_fwd(); __syncthreads();
    if (tid < 36) {
      int r = tid / OD, d = tid % OD;
      float adec = pbd[d];
#pragma unroll
      for (int i = 0; i < HID; ++i) adec += hNew[r][i] * pWd[i * OD + d];
      float pr = fmaxf(adec, 0.f);
      float e = pr - Y[(size_t)t2 * BATCH * OD + (size_t)(row0 + r) * OD + d];
      errACC += e * e;
    }
    if (tid < 128) { int r = tid >> 5, i = tid & 31; hOld[r][i] = hNew[r][i]; }
    __syncthreads();
  }

  if (tid < 36) (&red[0][0])[tid] = errACC;
  __syncthreads();
  if (tid == 0) {
    float sum = 0.f;
    for (int q = 0; q < 36; ++q) sum += (&red[0][0])[q];
    errp[bid] = sum;
    __threadfence();
    __hip_atomic_store(&tags2[bid], 1u, __ATOMIC_RELEASE, __HIP_MEMORY_SCOPE_AGENT);
  }

  // block 0 produces the 33 outputs
  if (bid == 0) {
    if (tid < NB) {
      spin_ge(&tags2[tid], 1u);
      spin_ge(&tags[0 * NB + tid], 401u);
    }
    __syncthreads();
    __threadfence();
    if (tid == 0) {
      float sum = 0.f;
      for (int b = 0; b < NB; ++b) sum += errp[b];
      out[0] = sum * (1.f / 1024.f);
    }
    if (tid >= 64 && tid < 96) {
      int c = tid - 64;
      float sum = 0.f;
      for (int b = 0; b < NB; ++b) sum += part[(size_t)b * SU + c];
      out[1 + c] = sum * (1.f / 1024.f);
    }
  }
}

extern "C" void kernel_launch(void* const* d_in, const int* in_sizes, int n_in,
                              void* d_out, int out_size, void* d_ws, size_t ws_size,
                              hipStream_t stream) {
  (void)in_sizes; (void)n_in; (void)out_size;
  if (ws_size < WS_NEEDED) return;

  const float* X   = (const float*)d_in[0];
  const float* Y   = (const float*)d_in[1];
  const float* W1  = (const float*)d_in[2];
  const float* b1  = (const float*)d_in[3];
  const float* W2  = (const float*)d_in[4];
  const float* b2  = (const float*)d_in[5];
  const float* W3  = (const float*)d_in[6];
  const float* b3  = (const float*)d_in[7];
  const float* W4  = (const float*)d_in[8];
  const float* b4  = (const float*)d_in[9];
  const float* Wih = (const float*)d_in[10];
  const float* Whh = (const float*)d_in[11];
  const float* bih = (const float*)d_in[12];
  const float* bhh = (const float*)d_in[13];
  const float* Wd  = (const float*)d_in[14];
  const float* bd  = (const float*)d_in[15];

  // zero the tag regions (tags + tags2 = first 3072 bytes)
  hipMemsetAsync(d_ws, 0, 3072, stream);
  prep_kernel<<<128, 256, 0, stream>>>(Wih, Whh, W2, W3, W4, (char*)d_ws);
  emb_kernel<<<NB, NT, 0, stream>>>(X, Y, W1, b1, W2, b2, W3, b3, W4, b4,
                                    Wih, Whh, bih, bhh, Wd, bd,
                                    (char*)d_ws, (float*)d_out);
}

// Round 6
// 16200.546 us; speedup vs baseline: 2.9953x; 2.1724x over previous
//
#include <hip/hip_runtime.h>

#define NB 256
#define NT 512

constexpr int BATCH = 1024;
constexpr int TSTEPS = 20;
constexpr int IND = 13;
constexpr int OD = 9;
constexpr int SU = 32;
constexpr int HID = 32;
constexpr int ITERS = 20;
constexpr float LR = 0.1f;
constexpr float AB1 = 0.9f;
constexpr float AB2 = 0.999f;
constexpr float AEPS = 1e-8f;

// bounded-spin cap: expected waits are ~µs; this is seconds. On trip, the
// block proceeds -> run terminates with wrong output instead of hanging.
constexpr unsigned SPIN_CAP = 1u << 27;

// workspace byte offsets
constexpr size_t OFF_CNT   = 0;        // u32 [4]: cnt[2] slot counters, cnt2, pad
                                       // (zeroed by memset)
constexpr size_t OFF_ERRP  = 3072;     // f32 [NB]
constexpr size_t OFF_PART  = 4096;     // f32 [2][NB][SU]        -> 69632
constexpr size_t OFF_WIHT  = 69632;    // f32 [45][32]           -> 75392
constexpr size_t OFF_WHHT  = 75392;    // f32 [32][32]           -> 79488
constexpr size_t OFF_W2T   = 79488;    // f32 [256][128]         -> 210560
constexpr size_t OFF_W3T   = 210560;   // f32 [256][256]         -> 472704
constexpr size_t OFF_W4T   = 472704;   // f32 [32][256]          -> 505472
constexpr size_t WS_NEEDED = 505472;

// NO __threadfence() anywhere: agent-scope acq_rel fences emit buffer_inv on
// gfx950, which invalidates the XCD's L2 every iteration and forces all weight
// traffic to L3 (~2.5 TB/s plateau = the measured 88 us/iter). Cross-block
// data instead uses per-instruction coherent (agent-scope atomic) ld/st.
__device__ __forceinline__ float ld_coh_f32(const float* p) {
  return __hip_atomic_load(p, __ATOMIC_RELAXED, __HIP_MEMORY_SCOPE_AGENT);
}
__device__ __forceinline__ void st_coh_f32(float* p, float v) {
  __hip_atomic_store(p, v, __ATOMIC_RELAXED, __HIP_MEMORY_SCOPE_AGENT);
}

__device__ __forceinline__ void fma4(float4& a, const float4 w, const float h) {
  a.x += w.x * h; a.y += w.y * h; a.z += w.z * h; a.w += w.w * h;
}
__device__ __forceinline__ float dot4(const float4 a, const float4 b) {
  return a.x * b.x + a.y * b.y + a.z * b.z + a.w * b.w;
}

__global__ void prep_kernel(const float* __restrict__ Wih,
                            const float* __restrict__ Whh,
                            const float* __restrict__ W2,
                            const float* __restrict__ W3,
                            const float* __restrict__ W4,
                            char* __restrict__ ws) {
  float* WihT = reinterpret_cast<float*>(ws + OFF_WIHT);
  float* WhhT = reinterpret_cast<float*>(ws + OFF_WHHT);
  float* W2T  = reinterpret_cast<float*>(ws + OFF_W2T);
  float* W3T  = reinterpret_cast<float*>(ws + OFF_W3T);
  float* W4T  = reinterpret_cast<float*>(ws + OFF_W4T);
  int tid = blockIdx.x * blockDim.x + threadIdx.x;
  int nt = gridDim.x * blockDim.x;
  for (int idx = tid; idx < 32 * 45; idx += nt) {
    int i = idx / 45, c = idx % 45;
    WihT[c * 32 + i] = Wih[idx];
  }
  for (int idx = tid; idx < 32 * 32; idx += nt) {
    int i = idx >> 5, j = idx & 31;
    WhhT[j * 32 + i] = Whh[idx];
  }
  // W2 [128][256] -> W2T [256][128]
  for (int idx = tid; idx < 256 * 128; idx += nt) {
    int k = idx >> 7, j = idx & 127;
    W2T[idx] = W2[j * 256 + k];
  }
  // W3 [256][256] -> W3T [256][256]
  for (int idx = tid; idx < 256 * 256; idx += nt) {
    int k = idx >> 8, j = idx & 255;
    W3T[idx] = W3[j * 256 + k];
  }
  // W4 [256][32] -> W4T [32][256]
  for (int idx = tid; idx < 32 * 256; idx += nt) {
    int k = idx >> 8, j = idx & 255;
    W4T[idx] = W4[j * 32 + k];
  }
}

__global__ __launch_bounds__(NT) void emb_kernel(
    const float* __restrict__ X, const float* __restrict__ Y,
    const float* __restrict__ pW1, const float* __restrict__ pb1,
    const float* __restrict__ pW2, const float* __restrict__ pb2,
    const float* __restrict__ pW3, const float* __restrict__ pb3,
    const float* __restrict__ pW4, const float* __restrict__ pb4,
    const float* __restrict__ pWih, const float* __restrict__ pWhh,
    const float* __restrict__ pbih, const float* __restrict__ pbhh,
    const float* __restrict__ pWd, const float* __restrict__ pbd,
    char* __restrict__ ws, float* __restrict__ out) {
  const int tid = threadIdx.x;
  const int bid = blockIdx.x;
  const int row0 = bid * 4;

  unsigned* cnt  = reinterpret_cast<unsigned*>(ws + OFF_CNT);     // [2] + cnt2
  float* errp = reinterpret_cast<float*>(ws + OFF_ERRP);          // [NB]
  float* part = reinterpret_cast<float*>(ws + OFF_PART);          // [2][NB][SU]
  const float* WihT = reinterpret_cast<const float*>(ws + OFF_WIHT);
  const float* WhhT = reinterpret_cast<const float*>(ws + OFF_WHHT);
  const float* W2T  = reinterpret_cast<const float*>(ws + OFF_W2T);
  const float* W3T  = reinterpret_cast<const float*>(ws + OFF_W3T);
  const float* W4T  = reinterpret_cast<const float*>(ws + OFF_W4T);

  __shared__ alignas(16) float s[4][SU];
  __shared__ alignas(16) float mAd[4][SU];
  __shared__ alignas(16) float vAd[4][SU];
  __shared__ alignas(16) float hOld[4][HID];
  __shared__ alignas(16) float hNew[4][HID];
  __shared__ alignas(16) float h1[4][128];
  __shared__ alignas(16) float h2[4][256];
  __shared__ alignas(16) float h3[4][256];
  __shared__ alignas(16) float wv[4][SU];
  __shared__ alignas(16) float da[4][HID];
  __shared__ alignas(16) float dwb[4][SU];
  __shared__ alignas(16) float dsb[4][SU];
  __shared__ alignas(16) float red2[8192];   // 32 KB k-split partial buffer
  __shared__ float xs[4][IND];
  __shared__ float ysd[4][OD];
  __shared__ float dadec[4][OD];
  __shared__ float mu[SU];
  __shared__ float red[8][SU];

  // bounded spin until *cntp >= tgt (returns regardless after SPIN_CAP polls)
  auto spin_ge = [&](unsigned* cntp, unsigned tgt) {
    unsigned n = 0;
    while (__hip_atomic_load(cntp, __ATOMIC_RELAXED,
                             __HIP_MEMORY_SCOPE_AGENT) < tgt) {
      __builtin_amdgcn_s_sleep(1);
      if (++n >= SPIN_CAP) break;
    }
  };

  // ---- layer routines. Pattern: k-split compute (float4 weight loads,
  // each load feeds all 4 rows = 16 FMA/load) -> barrier -> reduce.

  // L1 fwd: h1[4][128] = relu(s[4][32] @ W1[32][128] + b1)
  auto fwd_l1 = [&]() {
    if (tid < 256) {
      int j0 = (tid & 31) * 4, kg = tid >> 5;  // 8 kg x 4 k
      float4 a0 = {0,0,0,0}, a1 = a0, a2 = a0, a3 = a0;
#pragma unroll
      for (int q = 0; q < 4; ++q) {
        int k = kg * 4 + q;
        float4 w = *reinterpret_cast<const float4*>(pW1 + k * 128 + j0);
        fma4(a0, w, s[0][k]); fma4(a1, w, s[1][k]);
        fma4(a2, w, s[2][k]); fma4(a3, w, s[3][k]);
      }
      *reinterpret_cast<float4*>(&red2[(kg * 4 + 0) * 128 + j0]) = a0;
      *reinterpret_cast<float4*>(&red2[(kg * 4 + 1) * 128 + j0]) = a1;
      *reinterpret_cast<float4*>(&red2[(kg * 4 + 2) * 128 + j0]) = a2;
      *reinterpret_cast<float4*>(&red2[(kg * 4 + 3) * 128 + j0]) = a3;
    }
    __syncthreads();
    int r = tid >> 7, j = tid & 127;
    float sum = pb1[j];
#pragma unroll
    for (int g = 0; g < 8; ++g) sum += red2[(g * 4 + r) * 128 + j];
    h1[r][j] = fmaxf(sum, 0.f);
  };

  // wide fwd: hout[4][256] = relu(hin[4][K] @ W[K][256] + bias), K in {128,256}
  auto fwd_wide = [&](const float* __restrict__ W, const float* __restrict__ bias,
                      const float* hin, int K, float* hout) {
    {
      int j0 = (tid & 63) * 4, kg = tid >> 6;  // 8 kg
      int kn = K >> 3;                          // 16 or 32
      float4 a0 = {0,0,0,0}, a1 = a0, a2 = a0, a3 = a0;
#pragma unroll 8
      for (int q = 0; q < kn; ++q) {
        int k = kg * kn + q;
        float4 w = *reinterpret_cast<const float4*>(W + k * 256 + j0);
        fma4(a0, w, hin[0 * K + k]); fma4(a1, w, hin[1 * K + k]);
        fma4(a2, w, hin[2 * K + k]); fma4(a3, w, hin[3 * K + k]);
      }
      *reinterpret_cast<float4*>(&red2[(kg * 4 + 0) * 256 + j0]) = a0;
      *reinterpret_cast<float4*>(&red2[(kg * 4 + 1) * 256 + j0]) = a1;
      *reinterpret_cast<float4*>(&red2[(kg * 4 + 2) * 256 + j0]) = a2;
      *reinterpret_cast<float4*>(&red2[(kg * 4 + 3) * 256 + j0]) = a3;
    }
    __syncthreads();
    int o = tid * 2, r = o >> 8, j = o & 255;
    float s0 = bias[j], s1 = bias[j + 1];
#pragma unroll
    for (int g = 0; g < 8; ++g) {
      float2 p = *reinterpret_cast<const float2*>(&red2[(g * 4 + r) * 256 + j]);
      s0 += p.x; s1 += p.y;
    }
    hout[r * 256 + j]     = fmaxf(s0, 0.f);
    hout[r * 256 + j + 1] = fmaxf(s1, 0.f);
  };

  // L4 fwd: wv[4][32] = h3[4][256] @ W4[256][32] + b4 (linear)
  auto fwd_l4 = [&]() {
    if (tid < 128) {
      int j0 = (tid & 7) * 4, kg = tid >> 3;  // 16 kg x 16 k
      float4 a0 = {0,0,0,0}, a1 = a0, a2 = a0, a3 = a0;
#pragma unroll 8
      for (int q = 0; q < 16; ++q) {
        int k = kg * 16 + q;
        float4 w = *reinterpret_cast<const float4*>(pW4 + k * 32 + j0);
        fma4(a0, w, h3[0][k]); fma4(a1, w, h3[1][k]);
        fma4(a2, w, h3[2][k]); fma4(a3, w, h3[3][k]);
      }
      *reinterpret_cast<float4*>(&red2[(kg * 4 + 0) * 32 + j0]) = a0;
      *reinterpret_cast<float4*>(&red2[(kg * 4 + 1) * 32 + j0]) = a1;
      *reinterpret_cast<float4*>(&red2[(kg * 4 + 2) * 32 + j0]) = a2;
      *reinterpret_cast<float4*>(&red2[(kg * 4 + 3) * 32 + j0]) = a3;
    }
    __syncthreads();
    if (tid < 128) {
      int r = tid >> 5, j = tid & 31;
      float sum = pb4[j];
#pragma unroll
      for (int g = 0; g < 16; ++g) sum += red2[(g * 4 + r) * 32 + j];
      wv[r][j] = sum;
    }
  };

  // RNN cell fwd: hNew = tanh(cat(x,w)@Wih^T + bih + hOld@Whh^T + bhh)
  auto rnn_fwd = [&]() {
    if (tid < 128) {
      int r = tid >> 5, i = tid & 31;
      float a = pbih[i] + pbhh[i];
#pragma unroll
      for (int c = 0; c < IND; ++c) a += xs[r][c] * WihT[c * 32 + i];
#pragma unroll 8
      for (int c = 0; c < SU; ++c) a += wv[r][c] * WihT[(13 + c) * 32 + i];
#pragma unroll 8
      for (int j = 0; j < HID; ++j) a += hOld[r][j] * WhhT[j * 32 + i];
      hNew[r][i] = tanhf(a);
    }
  };

  // bwd through a 256-wide output with TRANSPOSED weights WT[Kd][256]:
  // dmask[r][j] = (dmask[r][j] > 0) * sum_k din[r*Kd+k] WT[k*256+j]
  auto bwdT256 = [&](const float* __restrict__ WT, const float* din, int Kd,
                     float* dmask) {
    {
      int j0 = (tid & 63) * 4, kg = tid >> 6;  // 8 kg
      int kn = Kd >> 3;                         // 4 or 32
      float4 a0 = {0,0,0,0}, a1 = a0, a2 = a0, a3 = a0;
#pragma unroll 4
      for (int q = 0; q < kn; ++q) {
        int k = kg * kn + q;
        float4 w = *reinterpret_cast<const float4*>(WT + k * 256 + j0);
        fma4(a0, w, din[0 * Kd + k]); fma4(a1, w, din[1 * Kd + k]);
        fma4(a2, w, din[2 * Kd + k]); fma4(a3, w, din[3 * Kd + k]);
      }
      *reinterpret_cast<float4*>(&red2[(kg * 4 + 0) * 256 + j0]) = a0;
      *reinterpret_cast<float4*>(&red2[(kg * 4 + 1) * 256 + j0]) = a1;
      *reinterpret_cast<float4*>(&red2[(kg * 4 + 2) * 256 + j0]) = a2;
      *reinterpret_cast<float4*>(&red2[(kg * 4 + 3) * 256 + j0]) = a3;
    }
    __syncthreads();
    int o = tid * 2, r = o >> 8, j = o & 255;
    float s0 = 0.f, s1 = 0.f;
#pragma unroll
    for (int g = 0; g < 8; ++g) {
      float2 p = *reinterpret_cast<const float2*>(&red2[(g * 4 + r) * 256 + j]);
      s0 += p.x; s1 += p.y;
    }
    float m0 = dmask[r * 256 + j], m1 = dmask[r * 256 + j + 1];
    dmask[r * 256 + j]     = (m0 > 0.f) ? s0 : 0.f;
    dmask[r * 256 + j + 1] = (m1 > 0.f) ? s1 : 0.f;
  };

  // dh1[r][j<128] = mask(h1) * sum_{k<256} dh2[r][k] W2T[k*128+j]
  auto bwd_dh1 = [&]() {
    {
      int j0 = (tid & 31) * 4, kg = tid >> 5;  // 16 kg x 16 k
      float4 a0 = {0,0,0,0}, a1 = a0, a2 = a0, a3 = a0;
#pragma unroll 8
      for (int q = 0; q < 16; ++q) {
        int k = kg * 16 + q;
        float4 w = *reinterpret_cast<const float4*>(W2T + k * 128 + j0);
        fma4(a0, w, h2[0][k]); fma4(a1, w, h2[1][k]);
        fma4(a2, w, h2[2][k]); fma4(a3, w, h2[3][k]);
      }
      *reinterpret_cast<float4*>(&red2[(kg * 4 + 0) * 128 + j0]) = a0;
      *reinterpret_cast<float4*>(&red2[(kg * 4 + 1) * 128 + j0]) = a1;
      *reinterpret_cast<float4*>(&red2[(kg * 4 + 2) * 128 + j0]) = a2;
      *reinterpret_cast<float4*>(&red2[(kg * 4 + 3) * 128 + j0]) = a3;
    }
    __syncthreads();
    int r = tid >> 7, j = tid & 127;
    float sum = 0.f;
#pragma unroll
    for (int g = 0; g < 16; ++g) sum += red2[(g * 4 + r) * 128 + j];
    h1[r][j] = (h1[r][j] > 0.f) ? sum : 0.f;
  };

  // ds[r][k<32] = sum_{j<128} dh1[r][j] W1[k*128+j]
  auto bwd_ds = [&]() {
    if (tid < 256) {
      int k0 = (tid & 7) * 4, jg = (tid >> 3) & 31;
      int j0 = jg * 4;
      float4 g0 = *reinterpret_cast<const float4*>(&h1[0][j0]);
      float4 g1 = *reinterpret_cast<const float4*>(&h1[1][j0]);
      float4 g2 = *reinterpret_cast<const float4*>(&h1[2][j0]);
      float4 g3 = *reinterpret_cast<const float4*>(&h1[3][j0]);
      float4 a0, a1, a2, a3;
      float* A0 = &a0.x; float* A1 = &a1.x; float* A2 = &a2.x; float* A3 = &a3.x;
#pragma unroll
      for (int q = 0; q < 4; ++q) {
        int k = k0 + q;
        float4 w = *reinterpret_cast<const float4*>(pW1 + k * 128 + j0);
        A0[q] = dot4(w, g0); A1[q] = dot4(w, g1);
        A2[q] = dot4(w, g2); A3[q] = dot4(w, g3);
      }
      *reinterpret_cast<float4*>(&red2[jg * 128 + 0 * 32 + k0]) = a0;
      *reinterpret_cast<float4*>(&red2[jg * 128 + 1 * 32 + k0]) = a1;
      *reinterpret_cast<float4*>(&red2[jg * 128 + 2 * 32 + k0]) = a2;
      *reinterpret_cast<float4*>(&red2[jg * 128 + 3 * 32 + k0]) = a3;
    }
    __syncthreads();
    if (tid < 128) {
      int r = tid >> 5, k = tid & 31;
      float sum = 0.f;
#pragma unroll
      for (int g = 0; g < 32; ++g) sum += red2[g * 128 + r * 32 + k];
      dsb[r][k] = sum;
    }
  };

  // publish column partial-sums of current story into slot, then bump the
  // slot counter with RELEASE (orders the write-through part stores; no
  // cache-wide fence). Stores and RMW are all wave 0 -> vmcnt ordering.
  auto publish = [&](int pslot) {
    __syncthreads();
    if (tid < SU) {
      st_coh_f32(&part[(size_t)pslot * NB * SU + (size_t)bid * SU + tid],
                 s[0][tid] + s[1][tid] + s[2][tid] + s[3][tid]);
    }
    if (tid == 0)
      __hip_atomic_fetch_add(&cnt[pslot], 1u, __ATOMIC_RELEASE,
                             __HIP_MEMORY_SCOPE_AGENT);
  };

  // ---- init: story = 0, publish initial partials into slot 0
  if (tid < 128) { int r = tid >> 5, c = tid & 31; s[r][c] = 0.f; }
  publish(0);

  // ---- outer timesteps
  for (int ts = 0; ts < TSTEPS; ++ts) {
    if (tid < 4 * IND) {
      int r = tid / IND, c = tid % IND;
      xs[r][c] = X[(size_t)ts * BATCH * IND + (size_t)(row0 + r) * IND + c];
    }
    if (tid >= 64 && tid < 64 + 4 * OD) {
      int q = tid - 64; int r = q / OD, c = q % OD;
      ysd[r][c] = Y[(size_t)ts * BATCH * OD + (size_t)(row0 + r) * OD + c];
    }
    if (tid >= 128 && tid < 256) {
      int q = tid - 128; int r = q >> 5, c = q & 31;
      mAd[r][c] = 0.f; vAd[r][c] = 0.f; hOld[r][c] = 0.f;
    }
    float pb1t = 1.f, pb2t = 1.f;

    for (int it = 0; it < ITERS; ++it) {
      const int gi = ts * ITERS + it;
      const int p = gi & 1;
      pb1t *= AB1; pb2t *= AB2;

      // wait: slot p's monotonic counter. Publishes into slot p by the time
      // iter gi may start: init (p==0) + ends of iters p+1, p+3, ... < gi
      // => count = (gi/2 + 1) * NB.
      if (tid == 0) spin_ge(&cnt[p], (unsigned)(gi / 2 + 1) * (unsigned)NB);
      __syncthreads();

      // mu reduction (every block, redundantly); coherent loads (bypass
      // stale L1/L2 without invalidating them).
      if (tid < 256) {
        int c = tid & 31, grp = tid >> 5;
        const float* P = part + (size_t)p * NB * SU;
        float sum = 0.f;
#pragma unroll 8
        for (int b2 = grp * 32; b2 < grp * 32 + 32; ++b2)
          sum += ld_coh_f32(&P[b2 * SU + c]);
        red[grp][c] = sum;
      }
      __syncthreads();
      if (tid < SU) {
        float sum = 0.f;
#pragma unroll
        for (int g2 = 0; g2 < 8; ++g2) sum += red[g2][tid];
        mu[tid] = sum * (1.f / 1024.f);
      }
      __syncthreads();

      // ---- forward
      fwd_l1(); __syncthreads();
      fwd_wide(pW2, pb2, &h1[0][0], 128, &h2[0][0]); __syncthreads();
      fwd_wide(pW3, pb3, &h2[0][0], 256, &h3[0][0]); __syncthreads();
      fwd_l4(); __syncthreads();
      rnn_fwd(); __syncthreads();

      if (tid < 36) {  // decoder + d(err)/d(adec)
        int r = tid / OD, d = tid % OD;
        float adec = pbd[d];
#pragma unroll
        for (int i = 0; i < HID; ++i) adec += hNew[r][i] * pWd[i * OD + d];
        float pr = fmaxf(adec, 0.f);
        dadec[r][d] = (adec > 0.f) ? (2.f / 1024.f) * (pr - ysd[r][d]) : 0.f;
      }
      __syncthreads();

      if (tid < 128) {  // d h_new -> da (through tanh)
        int r = tid >> 5, i = tid & 31;
        float t1 = 0.f;
#pragma unroll
        for (int d = 0; d < OD; ++d) t1 += dadec[r][d] * pWd[i * OD + d];
        float hn = hNew[r][i];
        da[r][i] = t1 * (1.f - hn * hn);
      }
      __syncthreads();

      if (tid < 128) {  // dw_k = sum_i da_i Wih[i][13+k]
        int r = tid >> 5, k = tid & 31;
        float t2 = 0.f;
#pragma unroll 8
        for (int i = 0; i < HID; ++i) t2 += da[r][i] * WihT[(13 + k) * 32 + i];
        dwb[r][k] = t2;
      }
      __syncthreads();

      // ---- backward through hypernet (in-place with relu masks)
      bwdT256(W4T, &dwb[0][0], 32, &h3[0][0]); __syncthreads();
      bwdT256(W3T, &h3[0][0], 256, &h2[0][0]); __syncthreads();
      bwd_dh1(); __syncthreads();
      bwd_ds(); __syncthreads();

      // ---- Adam update + hidden carry
      if (tid < 128) {
        int r = tid >> 5, c = tid & 31;
        float sv = s[r][c];
        float g = dsb[r][c] + (sv - mu[c]) * (2.f / 1023.f) + sv * (2e-4f / 1024.f);
        float m2 = AB1 * mAd[r][c] + (1.f - AB1) * g;
        float v2 = AB2 * vAd[r][c] + (1.f - AB2) * g * g;
        mAd[r][c] = m2; vAd[r][c] = v2;
        float mh = m2 / (1.f - pb1t);
        float vh = v2 / (1.f - pb2t);
        s[r][c] = sv - LR * mh / (sqrtf(vh) + AEPS);
        hOld[r][c] = hNew[r][c];
      }

      publish((gi + 1) & 1);
    }
  }

  // ---- final evaluation: w = hyper(final story) (final story partials were
  // published into slot 0 at end of iter 399)
  fwd_l1(); __syncthreads();
  fwd_wide(pW2, pb2, &h1[0][0], 128, &h2[0][0]); __syncthreads();
  fwd_wide(pW3, pb3, &h2[0][0], 256, &h3[0][0]); __syncthreads();
  fwd_l4(); __syncthreads();

  if (tid < 128) { int r = tid >> 5, i = tid & 31; hOld[r][i] = 0.f; }
  __syncthreads();

  float errACC = 0.f;
  for (int t2 = 0; t2 < TSTEPS; ++t2) {
    if (tid < 4 * IND) {
      int r = tid / IND, c = tid % IND;
      xs[r][c] = X[(size_t)t2 * BATCH * IND + (size_t)(row0 + r) * IND + c];
    }
    __syncthreads();
    rnn_fwd(); __syncthreads();
    if (tid < 36) {
      int r = tid / OD, d = tid % OD;
      float adec = pbd[d];
#pragma unroll
      for (int i = 0; i < HID; ++i) adec += hNew[r][i] * pWd[i * OD + d];
      float pr = fmaxf(adec, 0.f);
      float e = pr - Y[(size_t)t2 * BATCH * OD + (size_t)(row0 + r) * OD + d];
      errACC += e * e;
    }
    if (tid < 128) { int r = tid >> 5, i = tid & 31; hOld[r][i] = hNew[r][i]; }
    __syncthreads();
  }

  if (tid < 36) (&red[0][0])[tid] = errACC;
  __syncthreads();
  if (tid == 0) {
    float sum = 0.f;
    for (int q = 0; q < 36; ++q) sum += (&red[0][0])[q];
    st_coh_f32(&errp[bid], sum);
    __hip_atomic_fetch_add(&cnt[2], 1u, __ATOMIC_RELEASE,
                           __HIP_MEMORY_SCOPE_AGENT);
  }

  // block 0 produces the 33 outputs
  if (bid == 0) {
    if (tid == 0) {
      spin_ge(&cnt[2], (unsigned)NB);
      // slot 0 publishes: init + ends of odd iters 1..399 = 201 per block
      spin_ge(&cnt[0], (unsigned)(TSTEPS * ITERS / 2 + 1) * (unsigned)NB);
    }
    __syncthreads();
    if (tid == 0) {
      float sum = 0.f;
      for (int b = 0; b < NB; ++b) sum += ld_coh_f32(&errp[b]);
      out[0] = sum * (1.f / 1024.f);
    }
    if (tid >= 64 && tid < 96) {
      int c = tid - 64;
      float sum = 0.f;
      for (int b = 0; b < NB; ++b)
        sum += ld_coh_f32(&part[(size_t)b * SU + c]);
      out[1 + c] = sum * (1.f / 1024.f);
    }
  }
}

extern "C" void kernel_launch(void* const* d_in, const int* in_sizes, int n_in,
                              void* d_out, int out_size, void* d_ws, size_t ws_size,
                              hipStream_t stream) {
  (void)in_sizes; (void)n_in; (void)out_size;
  if (ws_size < WS_NEEDED) return;

  const float* X   = (const float*)d_in[0];
  const float* Y   = (const float*)d_in[1];
  const float* W1  = (const float*)d_in[2];
  const float* b1  = (const float*)d_in[3];
  const float* W2  = (const float*)d_in[4];
  const float* b2  = (const float*)d_in[5];
  const float* W3  = (const float*)d_in[6];
  const float* b3  = (const float*)d_in[7];
  const float* W4  = (const float*)d_in[8];
  const float* b4  = (const float*)d_in[9];
  const float* Wih = (const float*)d_in[10];
  const float* Whh = (const float*)d_in[11];
  const float* bih = (const float*)d_in[12];
  const float* bhh = (const float*)d_in[13];
  const float* Wd  = (const float*)d_in[14];
  const float* bd  = (const float*)d_in[15];

  // zero the counter region
  hipMemsetAsync(d_ws, 0, 3072, stream);
  prep_kernel<<<128, 256, 0, stream>>>(Wih, Whh, W2, W3, W4, (char*)d_ws);
  emb_kernel<<<NB, NT, 0, stream>>>(X, Y, W1, b1, W2, b2, W3, b3, W4, b4,
                                    Wih, Whh, bih, bhh, Wd, bd,
                                    (char*)d_ws, (float*)d_out);
}

// Round 7
// 13263.625 us; speedup vs baseline: 3.6585x; 1.2214x over previous
//
#include <hip/hip_runtime.h>

#define NB 256
#define NT 1024

constexpr int BATCH = 1024;
constexpr int TSTEPS = 20;
constexpr int IND = 13;
constexpr int OD = 9;
constexpr int SU = 32;
constexpr int HID = 32;
constexpr int ITERS = 20;
constexpr float LR = 0.1f;
constexpr float AB1 = 0.9f;
constexpr float AB2 = 0.999f;
constexpr float AEPS = 1e-8f;

// bounded-spin cap: expected waits are ~µs; this is seconds. On trip, the
// block proceeds -> run terminates with wrong output instead of hanging.
constexpr unsigned SPIN_CAP = 1u << 27;

// workspace byte offsets
constexpr size_t OFF_CNT   = 0;        // u32 [4]: cnt[2] slot counters, cnt2
constexpr size_t OFF_ERRP  = 3072;     // f32 [NB]
constexpr size_t OFF_PART  = 4096;     // f32 [2][NB][SU]        -> 69632
constexpr size_t OFF_WIHT  = 69632;    // f32 [45][32]           -> 75392
constexpr size_t OFF_WHHT  = 75392;    // f32 [32][32]           -> 79488
constexpr size_t OFF_W2T   = 79488;    // f32 [256][128]         -> 210560
constexpr size_t OFF_W3T   = 210560;   // f32 [256][256]         -> 472704
constexpr size_t OFF_W4T   = 472704;   // f32 [32][256]          -> 505472
constexpr size_t WS_NEEDED = 505472;

// NO __threadfence(): agent-scope acq_rel fences emit buffer_inv on gfx950
// (invalidates XCD L2 -> all weight traffic falls to L3). Cross-block data
// uses per-instruction coherent (agent-scope relaxed atomic) ld/st instead.
__device__ __forceinline__ float ld_coh_f32(const float* p) {
  return __hip_atomic_load(p, __ATOMIC_RELAXED, __HIP_MEMORY_SCOPE_AGENT);
}
__device__ __forceinline__ void st_coh_f32(float* p, float v) {
  __hip_atomic_store(p, v, __ATOMIC_RELAXED, __HIP_MEMORY_SCOPE_AGENT);
}

__device__ __forceinline__ void fma4(float4& a, const float4 w, const float h) {
  a.x += w.x * h; a.y += w.y * h; a.z += w.z * h; a.w += w.w * h;
}
__device__ __forceinline__ float dot4(const float4 a, const float4 b) {
  return a.x * b.x + a.y * b.y + a.z * b.z + a.w * b.w;
}

__global__ void prep_kernel(const float* __restrict__ Wih,
                            const float* __restrict__ Whh,
                            const float* __restrict__ W2,
                            const float* __restrict__ W3,
                            const float* __restrict__ W4,
                            char* __restrict__ ws) {
  float* WihT = reinterpret_cast<float*>(ws + OFF_WIHT);
  float* WhhT = reinterpret_cast<float*>(ws + OFF_WHHT);
  float* W2T  = reinterpret_cast<float*>(ws + OFF_W2T);
  float* W3T  = reinterpret_cast<float*>(ws + OFF_W3T);
  float* W4T  = reinterpret_cast<float*>(ws + OFF_W4T);
  int tid = blockIdx.x * blockDim.x + threadIdx.x;
  int nt = gridDim.x * blockDim.x;
  for (int idx = tid; idx < 32 * 45; idx += nt) {
    int i = idx / 45, c = idx % 45;
    WihT[c * 32 + i] = Wih[idx];
  }
  for (int idx = tid; idx < 32 * 32; idx += nt) {
    int i = idx >> 5, j = idx & 31;
    WhhT[j * 32 + i] = Whh[idx];
  }
  for (int idx = tid; idx < 256 * 128; idx += nt) {   // W2T [256][128]
    int k = idx >> 7, j = idx & 127;
    W2T[idx] = W2[j * 256 + k];
  }
  for (int idx = tid; idx < 256 * 256; idx += nt) {   // W3T [256][256]
    int k = idx >> 8, j = idx & 255;
    W3T[idx] = W3[j * 256 + k];
  }
  for (int idx = tid; idx < 32 * 256; idx += nt) {    // W4T [32][256]
    int k = idx >> 8, j = idx & 255;
    W4T[idx] = W4[j * 32 + k];
  }
}

__global__ __launch_bounds__(NT) void emb_kernel(
    const float* __restrict__ X, const float* __restrict__ Y,
    const float* __restrict__ pW1, const float* __restrict__ pb1,
    const float* __restrict__ pW2, const float* __restrict__ pb2,
    const float* __restrict__ pW3, const float* __restrict__ pb3,
    const float* __restrict__ pW4, const float* __restrict__ pb4,
    const float* __restrict__ pWih, const float* __restrict__ pWhh,
    const float* __restrict__ pbih, const float* __restrict__ pbhh,
    const float* __restrict__ pWd, const float* __restrict__ pbd,
    char* __restrict__ ws, float* __restrict__ out) {
  const int tid = threadIdx.x;
  const int bid = blockIdx.x;
  const int row0 = bid * 4;
  // two 512-thread sub-blocks; sub s owns rows {2s, 2s+1}
  const int t  = tid & 511;
  const int rA = (tid >> 9) * 2, rB = rA + 1;

  unsigned* cnt = reinterpret_cast<unsigned*>(ws + OFF_CNT);      // [2] + cnt2
  float* errp = reinterpret_cast<float*>(ws + OFF_ERRP);          // [NB]
  float* part = reinterpret_cast<float*>(ws + OFF_PART);          // [2][NB][SU]
  const float* WihT = reinterpret_cast<const float*>(ws + OFF_WIHT);
  const float* WhhT = reinterpret_cast<const float*>(ws + OFF_WHHT);
  const float* W2T  = reinterpret_cast<const float*>(ws + OFF_W2T);
  const float* W3T  = reinterpret_cast<const float*>(ws + OFF_W3T);
  const float* W4T  = reinterpret_cast<const float*>(ws + OFF_W4T);

  __shared__ alignas(16) float s[4][SU];
  __shared__ alignas(16) float mAd[4][SU];
  __shared__ alignas(16) float vAd[4][SU];
  __shared__ alignas(16) float hOld[4][HID];
  __shared__ alignas(16) float hNew[4][HID];
  __shared__ alignas(16) float h1[4][128];
  __shared__ alignas(16) float h2[4][256];
  __shared__ alignas(16) float h3[4][256];
  __shared__ alignas(16) float wv[4][SU];
  __shared__ alignas(16) float da[4][HID];
  __shared__ alignas(16) float dwb[4][SU];
  __shared__ alignas(16) float dsb[4][SU];
  __shared__ alignas(16) float red2[8192];   // 32 KB k-split partial buffer
  __shared__ float xs[4][IND];
  __shared__ float ysd[4][OD];
  __shared__ float dadec[4][OD];
  __shared__ float red[32][SU];              // mu partials / misc reduce

  auto spin_ge = [&](unsigned* cntp, unsigned tgt) {
    unsigned n = 0;
    while (__hip_atomic_load(cntp, __ATOMIC_RELAXED,
                             __HIP_MEMORY_SCOPE_AGENT) < tgt) {
      __builtin_amdgcn_s_sleep(1);
      if (++n >= SPIN_CAP) break;
    }
  };

  // ---- layer routines: per-sub k-split compute (float4 weight loads, each
  // feeding 2 rows x 4 cols = 8 FMA) -> barrier -> block-wide reduce.

  // L1 fwd: h1[4][128] = relu(s[4][32] @ W1[32][128] + b1)
  auto fwd_l1 = [&]() {
    if (t < 256) {
      int j0 = (t & 31) * 4, kg = t >> 5;  // 8 kg x 4 k
      float4 aA = {0,0,0,0}, aB = aA;
#pragma unroll
      for (int q = 0; q < 4; ++q) {
        int k = kg * 4 + q;
        float4 w = *reinterpret_cast<const float4*>(pW1 + k * 128 + j0);
        fma4(aA, w, s[rA][k]); fma4(aB, w, s[rB][k]);
      }
      *reinterpret_cast<float4*>(&red2[(kg * 4 + rA) * 128 + j0]) = aA;
      *reinterpret_cast<float4*>(&red2[(kg * 4 + rB) * 128 + j0]) = aB;
    }
    __syncthreads();
    if (tid < 512) {
      int r = tid >> 7, j = tid & 127;
      float sum = pb1[j];
#pragma unroll
      for (int g = 0; g < 8; ++g) sum += red2[(g * 4 + r) * 128 + j];
      h1[r][j] = fmaxf(sum, 0.f);
    }
  };

  // wide fwd: hout[4][256] = relu(hin[4][K] @ W[K][256] + bias), K in {128,256}
  auto fwd_wide = [&](const float* __restrict__ W, const float* __restrict__ bias,
                      const float* hin, int K, float* hout) {
    {
      int j0 = (t & 63) * 4, kg = t >> 6;  // 8 kg
      int kn = K >> 3;                      // 16 or 32
      float4 aA = {0,0,0,0}, aB = aA;
#pragma unroll 8
      for (int q = 0; q < kn; ++q) {
        int k = kg * kn + q;
        float4 w = *reinterpret_cast<const float4*>(W + k * 256 + j0);
        fma4(aA, w, hin[rA * K + k]); fma4(aB, w, hin[rB * K + k]);
      }
      *reinterpret_cast<float4*>(&red2[(kg * 4 + rA) * 256 + j0]) = aA;
      *reinterpret_cast<float4*>(&red2[(kg * 4 + rB) * 256 + j0]) = aB;
    }
    __syncthreads();
    {
      int r = tid >> 8, j = tid & 255;
      float s0 = bias[j];
#pragma unroll
      for (int g = 0; g < 8; ++g) s0 += red2[(g * 4 + r) * 256 + j];
      hout[r * 256 + j] = fmaxf(s0, 0.f);
    }
  };

  // L4 fwd: wv[4][32] = h3[4][256] @ W4[256][32] + b4 (linear)
  auto fwd_l4 = [&]() {
    if (t < 128) {
      int j0 = (t & 7) * 4, kg = t >> 3;  // 16 kg x 16 k
      float4 aA = {0,0,0,0}, aB = aA;
#pragma unroll 8
      for (int q = 0; q < 16; ++q) {
        int k = kg * 16 + q;
        float4 w = *reinterpret_cast<const float4*>(pW4 + k * 32 + j0);
        fma4(aA, w, h3[rA][k]); fma4(aB, w, h3[rB][k]);
      }
      *reinterpret_cast<float4*>(&red2[(kg * 4 + rA) * 32 + j0]) = aA;
      *reinterpret_cast<float4*>(&red2[(kg * 4 + rB) * 32 + j0]) = aB;
    }
    __syncthreads();
    if (tid < 128) {
      int r = tid >> 5, j = tid & 31;
      float sum = pb4[j];
#pragma unroll
      for (int g = 0; g < 16; ++g) sum += red2[(g * 4 + r) * 32 + j];
      wv[r][j] = sum;
    }
  };

  // RNN cell fwd: hNew = tanh(cat(x,w)@Wih^T + bih + hOld@Whh^T + bhh)
  auto rnn_fwd = [&]() {
    if (tid < 128) {
      int r = tid >> 5, i = tid & 31;
      float a = pbih[i] + pbhh[i];
#pragma unroll
      for (int c = 0; c < IND; ++c) a += xs[r][c] * WihT[c * 32 + i];
#pragma unroll 8
      for (int c = 0; c < SU; ++c) a += wv[r][c] * WihT[(13 + c) * 32 + i];
#pragma unroll 8
      for (int j = 0; j < HID; ++j) a += hOld[r][j] * WhhT[j * 32 + i];
      hNew[r][i] = tanhf(a);
    }
  };

  // bwd through 256-wide output with TRANSPOSED weights WT[Kd][256]
  auto bwdT256 = [&](const float* __restrict__ WT, const float* din, int Kd,
                     float* dmask) {
    {
      int j0 = (t & 63) * 4, kg = t >> 6;  // 8 kg
      int kn = Kd >> 3;                     // 4 or 32
      float4 aA = {0,0,0,0}, aB = aA;
#pragma unroll 4
      for (int q = 0; q < kn; ++q) {
        int k = kg * kn + q;
        float4 w = *reinterpret_cast<const float4*>(WT + k * 256 + j0);
        fma4(aA, w, din[rA * Kd + k]); fma4(aB, w, din[rB * Kd + k]);
      }
      *reinterpret_cast<float4*>(&red2[(kg * 4 + rA) * 256 + j0]) = aA;
      *reinterpret_cast<float4*>(&red2[(kg * 4 + rB) * 256 + j0]) = aB;
    }
    __syncthreads();
    {
      int r = tid >> 8, j = tid & 255;
      float s0 = 0.f;
#pragma unroll
      for (int g = 0; g < 8; ++g) s0 += red2[(g * 4 + r) * 256 + j];
      float m0 = dmask[r * 256 + j];
      dmask[r * 256 + j] = (m0 > 0.f) ? s0 : 0.f;
    }
  };

  // dh1[r][j<128] = mask(h1) * sum_{k<256} dh2[r][k] W2T[k*128+j]
  auto bwd_dh1 = [&]() {
    {
      int j0 = (t & 31) * 4, kg = t >> 5;  // 16 kg x 16 k
      float4 aA = {0,0,0,0}, aB = aA;
#pragma unroll 8
      for (int q = 0; q < 16; ++q) {
        int k = kg * 16 + q;
        float4 w = *reinterpret_cast<const float4*>(W2T + k * 128 + j0);
        fma4(aA, w, h2[rA][k]); fma4(aB, w, h2[rB][k]);
      }
      *reinterpret_cast<float4*>(&red2[(kg * 4 + rA) * 128 + j0]) = aA;
      *reinterpret_cast<float4*>(&red2[(kg * 4 + rB) * 128 + j0]) = aB;
    }
    __syncthreads();
    if (tid < 512) {
      int r = tid >> 7, j = tid & 127;
      float sum = 0.f;
#pragma unroll
      for (int g = 0; g < 16; ++g) sum += red2[(g * 4 + r) * 128 + j];
      h1[r][j] = (h1[r][j] > 0.f) ? sum : 0.f;
    }
  };

  // ds[r][k<32] = sum_{j<128} dh1[r][j] W1[k*128+j]
  auto bwd_ds = [&]() {
    if (t < 256) {
      int k0 = (t & 7) * 4, jg = t >> 3;  // 32 j-groups x 4 j
      int j0 = jg * 4;
      float4 gA = *reinterpret_cast<const float4*>(&h1[rA][j0]);
      float4 gB = *reinterpret_cast<const float4*>(&h1[rB][j0]);
      float4 aA, aB;
      float* A = &aA.x; float* Bp = &aB.x;
#pragma unroll
      for (int q = 0; q < 4; ++q) {
        int k = k0 + q;
        float4 w = *reinterpret_cast<const float4*>(pW1 + k * 128 + j0);
        A[q] = dot4(w, gA); Bp[q] = dot4(w, gB);
      }
      *reinterpret_cast<float4*>(&red2[jg * 128 + rA * 32 + k0]) = aA;
      *reinterpret_cast<float4*>(&red2[jg * 128 + rB * 32 + k0]) = aB;
    }
    __syncthreads();
    if (tid < 128) {
      int r = tid >> 5, k = tid & 31;
      float sum = 0.f;
#pragma unroll
      for (int g = 0; g < 32; ++g) sum += red2[g * 128 + r * 32 + k];
      dsb[r][k] = sum;
    }
  };

  // publish column partial-sums of current story into slot + bump counter
  auto publish = [&](int pslot) {
    __syncthreads();
    if (tid < SU) {
      st_coh_f32(&part[(size_t)pslot * NB * SU + (size_t)bid * SU + tid],
                 s[0][tid] + s[1][tid] + s[2][tid] + s[3][tid]);
    }
    if (tid == 0)
      __hip_atomic_fetch_add(&cnt[pslot], 1u, __ATOMIC_RELEASE,
                             __HIP_MEMORY_SCOPE_AGENT);
  };

  // ---- init: story = 0, publish initial partials into slot 0
  if (tid < 128) { int r = tid >> 5, c = tid & 31; s[r][c] = 0.f; }
  publish(0);

  // ---- outer timesteps
  for (int ts = 0; ts < TSTEPS; ++ts) {
    if (tid < 4 * IND) {
      int r = tid / IND, c = tid % IND;
      xs[r][c] = X[(size_t)ts * BATCH * IND + (size_t)(row0 + r) * IND + c];
    }
    if (tid >= 64 && tid < 64 + 4 * OD) {
      int q = tid - 64; int r = q / OD, c = q % OD;
      ysd[r][c] = Y[(size_t)ts * BATCH * OD + (size_t)(row0 + r) * OD + c];
    }
    if (tid >= 128 && tid < 256) {
      int q = tid - 128; int r = q >> 5, c = q & 31;
      mAd[r][c] = 0.f; vAd[r][c] = 0.f; hOld[r][c] = 0.f;
    }
    float pb1t = 1.f, pb2t = 1.f;

    for (int it = 0; it < ITERS; ++it) {
      const int gi = ts * ITERS + it;
      const int p = gi & 1;
      pb1t *= AB1; pb2t *= AB2;

      // ---- forward (independent of other blocks' iter-(gi-1) results)
      fwd_l1(); __syncthreads();
      fwd_wide(pW2, pb2, &h1[0][0], 128, &h2[0][0]); __syncthreads();
      fwd_wide(pW3, pb3, &h2[0][0], 256, &h3[0][0]); __syncthreads();
      fwd_l4(); __syncthreads();
      rnn_fwd(); __syncthreads();

      if (tid < 36) {  // decoder + d(err)/d(adec)
        int r = tid / OD, d = tid % OD;
        float adec = pbd[d];
#pragma unroll
        for (int i = 0; i < HID; ++i) adec += hNew[r][i] * pWd[i * OD + d];
        float pr = fmaxf(adec, 0.f);
        dadec[r][d] = (adec > 0.f) ? (2.f / 1024.f) * (pr - ysd[r][d]) : 0.f;
      }
      __syncthreads();

      if (tid < 128) {  // d h_new -> da (through tanh)
        int r = tid >> 5, i = tid & 31;
        float t1 = 0.f;
#pragma unroll
        for (int d = 0; d < OD; ++d) t1 += dadec[r][d] * pWd[i * OD + d];
        float hn = hNew[r][i];
        da[r][i] = t1 * (1.f - hn * hn);
      }
      __syncthreads();

      if (tid < 128) {  // dw_k = sum_i da_i Wih[i][13+k]
        int r = tid >> 5, k = tid & 31;
        float t2 = 0.f;
#pragma unroll 8
        for (int i = 0; i < HID; ++i) t2 += da[r][i] * WihT[(13 + k) * 32 + i];
        dwb[r][k] = t2;
      }
      __syncthreads();

      // ---- backward through hypernet (in-place with relu masks)
      bwdT256(W4T, &dwb[0][0], 32, &h3[0][0]); __syncthreads();
      bwdT256(W3T, &h3[0][0], 256, &h2[0][0]); __syncthreads();
      bwd_dh1(); __syncthreads();
      bwd_ds(); __syncthreads();

      // ---- handshake LATE: mu is only needed by Adam, so the wait on other
      // blocks' iter-(gi-1) publishes overlaps this block's fwd+bwd above.
      if (tid == 0) spin_ge(&cnt[p], (unsigned)(gi / 2 + 1) * (unsigned)NB);
      __syncthreads();

      {  // mu partial reduction (32 groups x 8 blocks), coherent loads
        int c = tid & 31, grp = tid >> 5;
        const float* P = part + (size_t)p * NB * SU;
        float sum = 0.f;
#pragma unroll
        for (int b2 = grp * 8; b2 < grp * 8 + 8; ++b2)
          sum += ld_coh_f32(&P[b2 * SU + c]);
        red[grp][c] = sum;
      }
      __syncthreads();

      // ---- Adam update (mu finalized inline) + hidden carry
      if (tid < 128) {
        int r = tid >> 5, c = tid & 31;
        float msum = 0.f;
#pragma unroll
        for (int g = 0; g < 32; ++g) msum += red[g][c];
        float muc = msum * (1.f / 1024.f);
        float sv = s[r][c];
        float g = dsb[r][c] + (sv - muc) * (2.f / 1023.f) + sv * (2e-4f / 1024.f);
        float m2 = AB1 * mAd[r][c] + (1.f - AB1) * g;
        float v2 = AB2 * vAd[r][c] + (1.f - AB2) * g * g;
        mAd[r][c] = m2; vAd[r][c] = v2;
        float mh = m2 / (1.f - pb1t);
        float vh = v2 / (1.f - pb2t);
        s[r][c] = sv - LR * mh / (sqrtf(vh) + AEPS);
        hOld[r][c] = hNew[r][c];
      }

      publish((gi + 1) & 1);
    }
  }

  // ---- final evaluation: w = hyper(final story)
  fwd_l1(); __syncthreads();
  fwd_wide(pW2, pb2, &h1[0][0], 128, &h2[0][0]); __syncthreads();
  fwd_wide(pW3, pb3, &h2[0][0], 256, &h3[0][0]); __syncthreads();
  fwd_l4(); __syncthreads();

  if (tid < 128) { int r = tid >> 5, i = tid & 31; hOld[r][i] = 0.f; }
  __syncthreads();

  float errACC = 0.f;
  for (int t2 = 0; t2 < TSTEPS; ++t2) {
    if (tid < 4 * IND) {
      int r = tid / IND, c = tid % IND;
      xs[r][c] = X[(size_t)t2 * BATCH * IND + (size_t)(row0 + r) * IND + c];
    }
    __syncthreads();
    rnn_fwd(); __syncthreads();
    if (tid < 36) {
      int r = tid / OD, d = tid % OD;
      float adec = pbd[d];
#pragma unroll
      for (int i = 0; i < HID; ++i) adec += hNew[r][i] * pWd[i * OD + d];
      float pr = fmaxf(adec, 0.f);
      float e = pr - Y[(size_t)t2 * BATCH * OD + (size_t)(row0 + r) * OD + d];
      errACC += e * e;
    }
    if (tid < 128) { int r = tid >> 5, i = tid & 31; hOld[r][i] = hNew[r][i]; }
    __syncthreads();
  }

  if (tid < 36) (&red[0][0])[tid] = errACC;
  __syncthreads();
  if (tid == 0) {
    float sum = 0.f;
    for (int q = 0; q < 36; ++q) sum += (&red[0][0])[q];
    st_coh_f32(&errp[bid], sum);
    __hip_atomic_fetch_add(&cnt[2], 1u, __ATOMIC_RELEASE,
                           __HIP_MEMORY_SCOPE_AGENT);
  }

  // block 0 produces the 33 outputs
  if (bid == 0) {
    if (tid == 0) {
      spin_ge(&cnt[2], (unsigned)NB);
      // slot 0 publishes: init + ends of odd iters 1..399 = 201 per block
      spin_ge(&cnt[0], (unsigned)(TSTEPS * ITERS / 2 + 1) * (unsigned)NB);
    }
    __syncthreads();
    if (tid == 0) {
      float sum = 0.f;
      for (int b = 0; b < NB; ++b) sum += ld_coh_f32(&errp[b]);
      out[0] = sum * (1.f / 1024.f);
    }
    if (tid >= 64 && tid < 96) {
      int c = tid - 64;
      float sum = 0.f;
      for (int b = 0; b < NB; ++b)
        sum += ld_coh_f32(&part[(size_t)b * SU + c]);
      out[1 + c] = sum * (1.f / 1024.f);
    }
  }
}

extern "C" void kernel_launch(void* const* d_in, const int* in_sizes, int n_in,
                              void* d_out, int out_size, void* d_ws, size_t ws_size,
                              hipStream_t stream) {
  (void)in_sizes; (void)n_in; (void)out_size;
  if (ws_size < WS_NEEDED) return;

  const float* X   = (const float*)d_in[0];
  const float* Y   = (const float*)d_in[1];
  const float* W1  = (const float*)d_in[2];
  const float* b1  = (const float*)d_in[3];
  const float* W2  = (const float*)d_in[4];
  const float* b2  = (const float*)d_in[5];
  const float* W3  = (const float*)d_in[6];
  const float* b3  = (const float*)d_in[7];
  const float* W4  = (const float*)d_in[8];
  const float* b4  = (const float*)d_in[9];
  const float* Wih = (const float*)d_in[10];
  const float* Whh = (const float*)d_in[11];
  const float* bih = (const float*)d_in[12];
  const float* bhh = (const float*)d_in[13];
  const float* Wd  = (const float*)d_in[14];
  const float* bd  = (const float*)d_in[15];

  hipMemsetAsync(d_ws, 0, 3072, stream);
  prep_kernel<<<128, 256, 0, stream>>>(Wih, Whh, W2, W3, W4, (char*)d_ws);
  emb_kernel<<<NB, NT, 0, stream>>>(X, Y, W1, b1, W2, b2, W3, b3, W4, b4,
                                    Wih, Whh, bih, bhh, Wd, bd,
                                    (char*)d_ws, (float*)d_out);
}